// Round 10
// baseline (596.853 us; speedup 1.0000x reference)
//
#include <hip/hip_runtime.h>

#define B_ 4
#define N_ 2048
#define C_ 1024
#define H_ 16
#define D_ 64
#define ROWS (B_ * N_)   // 8192

typedef __bf16 bf16x8 __attribute__((ext_vector_type(8)));
typedef float f32x4 __attribute__((ext_vector_type(4)));
typedef unsigned short ushort_t;

__device__ inline float b2f(ushort_t u) {
    union { unsigned int i; float f; } v; v.i = ((unsigned int)u) << 16; return v.f;
}
// round-to-nearest-even f32 -> bf16
__device__ inline ushort_t f2b(float f) {
    union { float f; unsigned int i; } v; v.f = f;
    unsigned int r = v.i + 0x7fffu + ((v.i >> 16) & 1u);
    return (ushort_t)(r >> 16);
}

// Runtime dtype detector: f32 arrays show huge bf16 exponents in even
// half-words; bf16 arrays of sane magnitude never do.
__device__ inline bool detect_f32(const ushort_t* u) {
    int huge = 0;
#pragma unroll
    for (int i = 0; i < 64; ++i) {
        int ex = (u[2 * i] >> 7) & 0xFF;
        huge |= (ex >= 0xC0) ? 1 : 0;
    }
    return huge != 0;
}

// ---------------------------------------------------------------------------
// Dtype hoist: convert an f32 (or copy a bf16) array to bf16 once, so GEMM
// staging runs the cheap bf16 path instead of per-tile f32->bf16 conversion.
// (Round-9 win: -124us total.)
// ---------------------------------------------------------------------------
__global__ __launch_bounds__(256) void cvt_bf16(
    const void* __restrict__ src, ushort_t* __restrict__ dst, int n_elts)
{
    const bool s32 = detect_f32((const ushort_t*)src);
    const int start = (blockIdx.x * 256 + threadIdx.x) * 8;
    const int stride = gridDim.x * 256 * 8;
    if (s32) {
        const float* s = (const float*)src;
        for (int i = start; i < n_elts; i += stride) {
            float4 a = *(const float4*)(s + i);
            float4 b = *(const float4*)(s + i + 4);
            ushort4 w0, w1;
            w0.x = f2b(a.x); w0.y = f2b(a.y); w0.z = f2b(a.z); w0.w = f2b(a.w);
            w1.x = f2b(b.x); w1.y = f2b(b.y); w1.z = f2b(b.z); w1.w = f2b(b.w);
            *(ushort4*)(dst + i)     = w0;
            *(ushort4*)(dst + i + 4) = w1;
        }
    } else {
        const ushort_t* s = (const ushort_t*)src;
        for (int i = start; i < n_elts; i += stride)
            *(uint4*)(dst + i) = *(const uint4*)(s + i);
    }
}

// ---------------------------------------------------------------------------
// GEMM: C[M,N] = A[M,K] * B[N,K]^T (+ bias[N]) (+ resid[M,N]).
// 128x128 tile, BK=32, 4 waves (2x2), each wave 64x64 = 4x4 subtiles.
// (round-4 proven inner loop; round-5's explicit double-buffer REGRESSED.)
// XCD swizzle (T1): all our grids have nwg % 8 == 0; remap so each XCD gets
// a contiguous chunk of work -> B-panels stay resident in its private L2
// instead of 8 XCDs each re-fetching every panel. Index-only, bijective.
// LN_QK: fused per-head (64-col) LayerNorm of the f32 accumulators in the
// epilogue (wave's 64-col span == one head). OUT_DYN: f32 out iff all five
// external inputs are f32.
// ---------------------------------------------------------------------------
template<bool HAS_BIAS, bool HAS_RES, bool A_EXT, bool B_EXT, bool OUT_DYN, bool LN_QK>
__global__ __launch_bounds__(256) void gemm_bt(
    const void* __restrict__ A,
    const void* __restrict__ Bm,
    const ushort_t* __restrict__ bias,
    const ushort_t* __restrict__ resid,
    void* __restrict__ Cc,
    int M, int N, int K,
    const ushort_t* e0, const ushort_t* e1, const ushort_t* e2,
    const ushort_t* e3, const ushort_t* e4)
{
    const bool a32 = A_EXT ? detect_f32((const ushort_t*)A)  : false;
    const bool b32 = B_EXT ? detect_f32((const ushort_t*)Bm) : false;
    bool out32 = false;
    if constexpr (OUT_DYN)
        out32 = detect_f32(e0) && detect_f32(e1) && detect_f32(e2) &&
                detect_f32(e3) && detect_f32(e4);

    __shared__ __align__(16) ushort_t As[128][32];
    __shared__ __align__(16) ushort_t Bs[128][32];
    const int tid  = threadIdx.x;
    const int wave = tid >> 6, lane = tid & 63;
    const int lo = lane & 15, hi = lane >> 4;

    // XCD-aware bijective remap (nwg % 8 == 0 for all launches here)
    const int nwg = gridDim.x * gridDim.y;
    const int w   = blockIdx.y * gridDim.x + blockIdx.x;
    const int cpx = nwg >> 3;
    const int wp  = (w & 7) * cpx + (w >> 3);
    const int bx  = wp % gridDim.x, by = wp / gridDim.x;

    const int bm = bx * 128, bn = by * 128;
    const int wm = (wave & 1) * 64,  wn = (wave >> 1) * 64;

    f32x4 acc[4][4] = {};

    for (int k0 = 0; k0 < K; k0 += 32) {
        if (a32) {
            const float* Af = (const float*)A;
#pragma unroll
            for (int i = 0; i < 4; ++i) {
                int c = tid + i * 256;
                int r = c >> 3, c4 = (c & 7) * 4;
                float4 v = *(const float4*)(Af + (size_t)(bm + r) * K + k0 + c4);
                ushort4 w4; w4.x = f2b(v.x); w4.y = f2b(v.y); w4.z = f2b(v.z); w4.w = f2b(v.w);
                *(ushort4*)(&As[r][c4]) = w4;
            }
        } else {
            const ushort_t* Ab = (const ushort_t*)A;
#pragma unroll
            for (int i = 0; i < 2; ++i) {
                int c = tid + i * 256;
                int r = c >> 2, c8 = (c & 3) * 8;
                *(uint4*)(&As[r][c8]) = *(const uint4*)(Ab + (size_t)(bm + r) * K + k0 + c8);
            }
        }
        if (b32) {
            const float* Bf = (const float*)Bm;
#pragma unroll
            for (int i = 0; i < 4; ++i) {
                int c = tid + i * 256;
                int r = c >> 3, c4 = (c & 7) * 4;
                float4 v = *(const float4*)(Bf + (size_t)(bn + r) * K + k0 + c4);
                ushort4 w4; w4.x = f2b(v.x); w4.y = f2b(v.y); w4.z = f2b(v.z); w4.w = f2b(v.w);
                *(ushort4*)(&Bs[r][c4]) = w4;
            }
        } else {
            const ushort_t* Bb = (const ushort_t*)Bm;
#pragma unroll
            for (int i = 0; i < 2; ++i) {
                int c = tid + i * 256;
                int r = c >> 2, c8 = (c & 3) * 8;
                *(uint4*)(&Bs[r][c8]) = *(const uint4*)(Bb + (size_t)(bn + r) * K + k0 + c8);
            }
        }
        __syncthreads();

        bf16x8 af[4], bfr[4];
#pragma unroll
        for (int i = 0; i < 4; ++i) af[i]  = *(const bf16x8*)(&As[wm + i * 16 + lo][hi * 8]);
#pragma unroll
        for (int j = 0; j < 4; ++j) bfr[j] = *(const bf16x8*)(&Bs[wn + j * 16 + lo][hi * 8]);
#pragma unroll
        for (int i = 0; i < 4; ++i)
#pragma unroll
            for (int j = 0; j < 4; ++j)
                acc[i][j] = __builtin_amdgcn_mfma_f32_16x16x32_bf16(af[i], bfr[j], acc[i][j], 0, 0, 0);
        __syncthreads();
    }

    if constexpr (LN_QK) {
        // per-head LN of q,k output columns (col0 = bn+wn, 64-aligned = 1 head)
        if (bn + wn < 2 * C_) {
#pragma unroll
            for (int i = 0; i < 4; ++i) {
#pragma unroll
                for (int r = 0; r < 4; ++r) {
                    float s = 0.0f, sq = 0.0f;
#pragma unroll
                    for (int j = 0; j < 4; ++j) {
                        float v = acc[i][j][r];
                        s += v; sq += v * v;
                    }
#pragma unroll
                    for (int off = 1; off < 16; off <<= 1) {
                        s  += __shfl_xor(s, off, 16);
                        sq += __shfl_xor(sq, off, 16);
                    }
                    const float mu   = s * (1.0f / 64.0f);
                    const float var  = sq * (1.0f / 64.0f) - mu * mu;
                    const float rstd = rsqrtf(var + 1e-5f);
#pragma unroll
                    for (int j = 0; j < 4; ++j)
                        acc[i][j][r] = (acc[i][j][r] - mu) * rstd;
                }
            }
        }
    }

#pragma unroll
    for (int i = 0; i < 4; ++i) {
#pragma unroll
        for (int j = 0; j < 4; ++j) {
            const int n = bn + wn + j * 16 + lo;
            float bv = HAS_BIAS ? b2f(bias[n]) : 0.0f;
#pragma unroll
            for (int r = 0; r < 4; ++r) {
                const int m = bm + wm + i * 16 + hi * 4 + r;
                float v = acc[i][j][r] + bv;
                if (HAS_RES) v += b2f(resid[(size_t)m * N + n]);
                if (OUT_DYN && out32) ((float*)Cc)[(size_t)m * N + n] = v;
                else                  ((ushort_t*)Cc)[(size_t)m * N + n] = f2b(v);
            }
        }
    }
}

// ---------------------------------------------------------------------------
// Fused LayerNorm(x) + FiLM: h = ln(x) * (1 + scale) + shift.
// ---------------------------------------------------------------------------
__global__ __launch_bounds__(256) void ln_film(
    const void* __restrict__ x,
    const ushort_t* __restrict__ se,
    ushort_t* __restrict__ h)
{
    const bool x32 = detect_f32((const ushort_t*)x);
    const int row = blockIdx.x;
    const int t = threadIdx.x;
    const int wave = t >> 6, lane = t & 63;

    float f0, f1, f2, f3;
    if (x32) {
        float4 v = *(const float4*)((const float*)x + (size_t)row * C_ + t * 4);
        f0 = v.x; f1 = v.y; f2 = v.z; f3 = v.w;
    } else {
        ushort4 v = *(const ushort4*)((const ushort_t*)x + (size_t)row * C_ + t * 4);
        f0 = b2f(v.x); f1 = b2f(v.y); f2 = b2f(v.z); f3 = b2f(v.w);
    }
    float s  = f0 + f1 + f2 + f3;
    float sq = f0 * f0 + f1 * f1 + f2 * f2 + f3 * f3;
#pragma unroll
    for (int off = 32; off >= 1; off >>= 1) {
        s  += __shfl_xor(s, off);
        sq += __shfl_xor(sq, off);
    }
    __shared__ float red[8];
    if (lane == 0) { red[wave] = s; red[4 + wave] = sq; }
    __syncthreads();
    s  = red[0] + red[1] + red[2] + red[3];
    sq = red[4] + red[5] + red[6] + red[7];
    const float mu   = s * (1.0f / C_);
    const float var  = sq * (1.0f / C_) - mu * mu;
    const float rstd = rsqrtf(var + 1e-5f);

    const ushort_t* ser = se + (size_t)row * (2 * C_);
    ushort4 sc = *(const ushort4*)(ser + t * 4);
    ushort4 sh = *(const ushort4*)(ser + C_ + t * 4);
    ushort4 out;
    out.x = f2b((f0 - mu) * rstd * (1.0f + b2f(sc.x)) + b2f(sh.x));
    out.y = f2b((f1 - mu) * rstd * (1.0f + b2f(sc.y)) + b2f(sh.y));
    out.z = f2b((f2 - mu) * rstd * (1.0f + b2f(sc.z)) + b2f(sh.z));
    out.w = f2b((f3 - mu) * rstd * (1.0f + b2f(sc.w)) + b2f(sh.w));
    *(ushort4*)(h + (size_t)row * C_ + t * 4) = out;
}

// ---------------------------------------------------------------------------
// V transpose: qkv (B,N,3,H,D) v-section -> vT (B,H,D,N). Coalesced both
// ways via LDS 64x64 tile. Grid: (B*H, N/64), 256 threads.
// ---------------------------------------------------------------------------
__global__ __launch_bounds__(256) void vtrans(
    const ushort_t* __restrict__ qkv,
    ushort_t* __restrict__ vT)
{
    const int bh = blockIdx.x, b = bh >> 4, hh = bh & 15;
    const int n0 = blockIdx.y * 64;
    const int t = threadIdx.x;
    __shared__ ushort_t Vs[64][65];

    const int r = t >> 2, c0 = (t & 3) * 16;   // row 0..63, col chunk of 16
    const ushort_t* src = qkv + (size_t)(b * N_ + n0 + r) * (3 * C_) + 2 * C_ + hh * D_;
#pragma unroll
    for (int i = 0; i < 16; ++i) Vs[r][c0 + i] = src[c0 + i];
    __syncthreads();
    // write rows of vT: thread t -> d = t>>2, n chunk (t&3)*16
    const int d = t >> 2, j0 = (t & 3) * 16;
    ushort_t* dst = vT + ((size_t)bh * D_ + d) * N_ + n0;
#pragma unroll
    for (int i = 0; i < 16; ++i) dst[j0 + i] = Vs[j0 + i][d];
}

// ---------------------------------------------------------------------------
// Flash attention v7 (16-wave). Grid: (B*H, N/256). 1024 threads = 16 waves,
// 16 q-rows each (256 q-rows/block). K/V tiles (64 keys x 128B) staged into
// double-buffered LDS shared by all 16 waves: waves 0-7 stage K, waves 8-15
// stage V (1 load + 1 ds_write per thread, wave-uniform split). LDS 68KB ->
// 2 blocks/CU x 16 waves = 32 waves/CU (100% ceiling; round-6's 8-wave
// config measured 41% at 3 blocks/CU), grid = 512 = exactly 2/CU (no tail),
// and K/V staged once per 256 q-rows (halved staging traffic). Single
// barrier per tile (write-late proof as v6). XOR-swizzled K/V LDS. Softmax
// exp2-domain with defer-max (THR=11); P via wave-private padded LDS slice.
// ---------------------------------------------------------------------------
__global__ __launch_bounds__(1024) void flash_attn(
    const ushort_t* __restrict__ qkv,
    const ushort_t* __restrict__ vT,
    ushort_t* __restrict__ o)
{
    const int bh = blockIdx.x, b = bh >> 4, hh = bh & 15;
    const int qb = blockIdx.y;
    const int tid = threadIdx.x;
    const int wave = tid >> 6, lane = tid & 63;
    const int lo = lane & 15, hi = lane >> 4;

    __shared__ __align__(16) ushort_t Ks[2][64 * 64];   // 8KB x2, swizzled chunks
    __shared__ __align__(16) ushort_t Vsh[2][64 * 64];  // 8KB x2
    __shared__ __align__(16) ushort_t Pl[16][16][72];   // wave-private, padded

    // staging: slot s (0..511) = one 16B chunk; waves 0-7 -> K, 8-15 -> V
    const bool isK = tid < 512;
    const int st = tid & 511;
    const int sr = st >> 3, sc = st & 7;
    const int lsw = sr * 64 + ((sc ^ (sr & 7)) * 8);    // swizzled ushort offset

    const int qrow = qb * 256 + wave * 16;
    // Q fragment (A-layout): row = qrow+lo, cols hi*8.. and 32+hi*8..
    const ushort_t* qp = qkv + (size_t)(b * N_ + qrow + lo) * (3 * C_) + hh * D_;
    const bf16x8 a0 = *(const bf16x8*)(qp + hi * 8);
    const bf16x8 a1 = *(const bf16x8*)(qp + 32 + hi * 8);

    // staging bases: K rows are keys (stride 3C); V rows are d (stride N)
    const ushort_t* Kg = qkv + (size_t)b * N_ * (3 * C_) + C_ + hh * D_;
    const ushort_t* Vg = vT + (size_t)bh * D_ * N_;

    f32x4 accO[4] = {};
    float m_r[4], l_r[4];
#pragma unroll
    for (int r = 0; r < 4; ++r) { m_r[r] = -1e30f; l_r[r] = 0.0f; }
    const f32x4 zero = {0.f, 0.f, 0.f, 0.f};
    const float SC = 0.125f * 1.44269504f;   // 1/sqrt(64) * log2(e)

    // swizzled read chunk offsets (in ushorts): chunks hi and 4+hi of a row,
    // row&7 == lo&7 for every fragment row this lane touches
    const int q0 = (hi ^ (lo & 7)) * 8;
    const int q1 = ((4 + hi) ^ (lo & 7)) * 8;

    // ---- prologue: stage tile 0 ----
    uint4 stg;
    if (isK) {
        stg = *(const uint4*)(Kg + (size_t)sr * (3 * C_) + sc * 8);
        *(uint4*)(&Ks[0][lsw]) = stg;
    } else {
        stg = *(const uint4*)(Vg + (size_t)sr * N_ + sc * 8);
        *(uint4*)(&Vsh[0][lsw]) = stg;
    }
    __syncthreads();
    int cur = 0;

    for (int kt = 0; kt < N_; kt += 64) {
        // T14 issue-early: launch tile t+1 global loads before compute
        const bool more = (kt + 64 < N_);
        if (more) {
            if (isK) stg = *(const uint4*)(Kg + (size_t)(kt + 64 + sr) * (3 * C_) + sc * 8);
            else     stg = *(const uint4*)(Vg + (size_t)sr * N_ + (kt + 64) + sc * 8);
        }
        __builtin_amdgcn_sched_barrier(0);   // keep load issue above compute

        // ---- QK^T for 4 groups of 16 keys ----
        const ushort_t* Kc = &Ks[cur][0];
        f32x4 S[4];
#pragma unroll
        for (int g = 0; g < 4; ++g) {
            const int R = g * 16 + lo;
            bf16x8 kl = *(const bf16x8*)(Kc + R * 64 + q0);
            bf16x8 kh = *(const bf16x8*)(Kc + R * 64 + q1);
            f32x4 s0 = __builtin_amdgcn_mfma_f32_16x16x32_bf16(a0, kl, zero, 0, 0, 0);
            S[g]     = __builtin_amdgcn_mfma_f32_16x16x32_bf16(a1, kh, s0,   0, 0, 0);
        }

        // ---- online softmax, exp2 domain ----
        float sv[4][4], pmax[4];
#pragma unroll
        for (int r = 0; r < 4; ++r) {
            float s0 = S[0][r] * SC, s1 = S[1][r] * SC;
            float s2 = S[2][r] * SC, s3 = S[3][r] * SC;
            sv[r][0] = s0; sv[r][1] = s1; sv[r][2] = s2; sv[r][3] = s3;
            float mx = fmaxf(fmaxf(s0, s1), fmaxf(s2, s3));
#pragma unroll
            for (int off = 1; off < 16; off <<= 1) mx = fmaxf(mx, __shfl_xor(mx, off, 16));
            pmax[r] = mx;
        }
        // defer-max: only rescale when some row's max grew past THR=11 (log2)
        int needi = 0;
#pragma unroll
        for (int r = 0; r < 4; ++r) needi |= (pmax[r] > m_r[r] + 11.0f) ? 1 : 0;
        if (__any(needi)) {
#pragma unroll
            for (int r = 0; r < 4; ++r) {
                float mnew  = fmaxf(m_r[r], pmax[r]);
                float alpha = __builtin_amdgcn_exp2f(m_r[r] - mnew);
                m_r[r] = mnew;
                l_r[r] *= alpha;
#pragma unroll
                for (int ds = 0; ds < 4; ++ds) accO[ds][r] *= alpha;
            }
        }
#pragma unroll
        for (int r = 0; r < 4; ++r) {
            float rs = 0.0f;
#pragma unroll
            for (int g = 0; g < 4; ++g) {
                float pv = __builtin_amdgcn_exp2f(sv[r][g] - m_r[r]);
                Pl[wave][hi * 4 + r][g * 16 + lo] = f2b(pv);
                rs += pv;
            }
#pragma unroll
            for (int off = 1; off < 16; off <<= 1) rs += __shfl_xor(rs, off, 16);
            l_r[r] += rs;
        }

        // intra-wave LDS RAW fence for Pl (wave-private slice, no barrier)
        asm volatile("s_waitcnt lgkmcnt(0)" ::: "memory");
        __builtin_amdgcn_sched_barrier(0);

        // ---- PV: P (16x64) x V^T tile (64d x 64k) ----
        bf16x8 pf0 = *(const bf16x8*)(&Pl[wave][lo][hi * 8]);        // keys 0..31
        bf16x8 pf1 = *(const bf16x8*)(&Pl[wave][lo][32 + hi * 8]);   // keys 32..63
        const ushort_t* Vc = &Vsh[cur][0];
#pragma unroll
        for (int ds = 0; ds < 4; ++ds) {
            const int R = ds * 16 + lo;
            bf16x8 vf0 = *(const bf16x8*)(Vc + R * 64 + q0);
            bf16x8 vf1 = *(const bf16x8*)(Vc + R * 64 + q1);
            accO[ds] = __builtin_amdgcn_mfma_f32_16x16x32_bf16(pf0, vf0, accO[ds], 0, 0, 0);
            accO[ds] = __builtin_amdgcn_mfma_f32_16x16x32_bf16(pf1, vf1, accO[ds], 0, 0, 0);
        }

        // ---- write-late: commit staged regs into the other buffer ----
        // (single barrier per tile: iter t's writes to buf^1 are separated
        //  from iter t-1's reads of buf^1 by iter t-1's trailing barrier)
        if (more) {
            if (isK) *(uint4*)(&Ks[cur ^ 1][lsw]) = stg;
            else     *(uint4*)(&Vsh[cur ^ 1][lsw]) = stg;
            __syncthreads();                   // staged tile visible to all
            cur ^= 1;
        }
    }

#pragma unroll
    for (int ds = 0; ds < 4; ++ds)
#pragma unroll
        for (int r = 0; r < 4; ++r) {
            const int row = qrow + hi * 4 + r;
            float val = accO[ds][r] / l_r[r];
            o[((size_t)(b * N_ + row)) * C_ + hh * D_ + ds * 16 + lo] = f2b(val);
        }
}

// ---------------------------------------------------------------------------
// Fallback simple attention (proven correct, slow) for small workspaces.
// ---------------------------------------------------------------------------
__global__ __launch_bounds__(256) void attn_simple(
    const ushort_t* __restrict__ qkv,
    ushort_t* __restrict__ o)
{
    const int bh = blockIdx.x, b = bh >> 4, hh = bh & 15;
    const int t = threadIdx.x, lane = t & 63, wave = t >> 6;
    __shared__ float sc[N_];
    __shared__ float qrow[D_];
    __shared__ float red[4];
    __shared__ float opart[4][D_];

    const size_t hbase = (size_t)b * N_ * (3 * C_) + (size_t)hh * D_;

    for (int qi = 0; qi < 128; ++qi) {
        const int qr = blockIdx.y * 128 + qi;
        if (t < 64) qrow[t] = b2f(qkv[hbase + (size_t)qr * (3 * C_) + t]);
        __syncthreads();

        float myS[8];
        float mymax = -1e30f;
#pragma unroll
        for (int jj = 0; jj < 8; ++jj) {
            const int j = t + jj * 256;
            const bf16x8* kr = (const bf16x8*)(qkv + hbase + (size_t)j * (3 * C_) + C_);
            float s = 0.0f;
#pragma unroll
            for (int c = 0; c < 8; ++c) {
                bf16x8 kv = kr[c];
#pragma unroll
                for (int e = 0; e < 8; ++e) s += qrow[c * 8 + e] * (float)kv[e];
            }
            s *= 0.125f;
            myS[jj] = s;
            mymax = fmaxf(mymax, s);
        }
#pragma unroll
        for (int off = 32; off >= 1; off >>= 1) mymax = fmaxf(mymax, __shfl_xor(mymax, off));
        if (lane == 0) red[wave] = mymax;
        __syncthreads();
        const float M = fmaxf(fmaxf(red[0], red[1]), fmaxf(red[2], red[3]));

        float mysum = 0.0f;
#pragma unroll
        for (int jj = 0; jj < 8; ++jj) {
            float p = __expf(myS[jj] - M);
            sc[t + jj * 256] = p;
            mysum += p;
        }
#pragma unroll
        for (int off = 32; off >= 1; off >>= 1) mysum += __shfl_xor(mysum, off);
        __syncthreads();
        if (lane == 0) red[wave] = mysum;
        __syncthreads();
        const float L = red[0] + red[1] + red[2] + red[3];

        float acc = 0.0f;
        const int d = lane;
        const ushort_t* vb = qkv + hbase + 2 * C_ + d;
        for (int j = wave * 512; j < wave * 512 + 512; ++j)
            acc += sc[j] * b2f(vb[(size_t)j * (3 * C_)]);
        opart[wave][d] = acc;
        __syncthreads();
        if (t < 64) {
            float val = (opart[0][t] + opart[1][t] + opart[2][t] + opart[3][t]) / L;
            o[((size_t)(b * N_ + qr)) * C_ + hh * D_ + t] = f2b(val);
        }
        __syncthreads();
    }
}

// ---------------------------------------------------------------------------
extern "C" void kernel_launch(void* const* d_in, const int* in_sizes, int n_in,
                              void* d_out, int out_size, void* d_ws, size_t ws_size,
                              hipStream_t stream)
{
    const void* x = nullptr; const void* emb = nullptr;
    const void* W_emb = nullptr; const void* b_emb = nullptr;
    const void* W_proj = nullptr; const void* W_out = nullptr;
    int big_seen = 0;
    for (int i = 0; i < n_in; ++i) {
        const int s = in_sizes[i];
        if      (s == ROWS * C_)   { if (big_seen++ == 0) x = d_in[i]; else emb = d_in[i]; }
        else if (s == 2 * C_ * C_) W_emb  = d_in[i];
        else if (s == 3 * C_ * C_) W_proj = d_in[i];
        else if (s == C_ * C_)     W_out  = d_in[i];
        else if (s == 2 * C_)      b_emb  = d_in[i];
    }

    // Workspace (80 MB budget), with dtype-hoisted bf16 copies:
    //   h        [0,16)    P2 -> P3
    //   se       [16,48)   P1 -> P2
    //   qkv      [16,64)   P3 (over dead se) -> P4
    //   o        [0,16)    P4 (over dead h)  -> P5
    //   vT       [64,80)   P4a -> P4b
    //   W_emb_bf [48,52)   P0 -> P1 (dead before qkv write at P3)
    //   emb_bf   [58,74)   P0 -> P1 (dead before vT write at P4a)
    //   W_proj_bf[74,80)   P0 -> P3 (clobbered by vT at P4a, already dead)
    char* ws = (char*)d_ws;
    const size_t MB = 1024 * 1024;
    ushort_t* h       = (ushort_t*)(ws);
    ushort_t* se      = (ushort_t*)(ws + 16 * MB);
    ushort_t* qkv     = (ushort_t*)(ws + 16 * MB);
    ushort_t* o       = (ushort_t*)(ws);
    ushort_t* vT      = (ushort_t*)(ws + 64 * MB);
    ushort_t* wemb_bf = (ushort_t*)(ws + 48 * MB);
    ushort_t* emb_bf  = (ushort_t*)(ws + 58 * MB);
    ushort_t* wprj_bf = (ushort_t*)(ws + 74 * MB);
    const bool use_flash = (ws_size >= 80 * MB);

    const ushort_t* e0 = (const ushort_t*)x;
    const ushort_t* e1 = (const ushort_t*)emb;
    const ushort_t* e2 = (const ushort_t*)W_emb;
    const ushort_t* e3 = (const ushort_t*)W_proj;
    const ushort_t* e4 = (const ushort_t*)W_out;

    // 0) hoist dtype conversion out of GEMM K-loops (f32 -> bf16 once)
    cvt_bf16<<<2048, 256, 0, stream>>>(emb,    emb_bf,  ROWS * C_);
    cvt_bf16<<<1024, 256, 0, stream>>>(W_emb,  wemb_bf, 2 * C_ * C_);
    cvt_bf16<<<1024, 256, 0, stream>>>(W_proj, wprj_bf, 3 * C_ * C_);

    // 1) se = emb @ W_emb^T + b_emb        (8192 x 2048 x 1024), all-bf16 path
    gemm_bt<true, false, false, false, false, false><<<dim3(ROWS / 128, 2048 / 128), 256, 0, stream>>>(
        emb_bf, wemb_bf, (const ushort_t*)b_emb, nullptr, se, ROWS, 2048, 1024,
        e0, e1, e2, e3, e4);
    // 2) h = ln(x) * (1 + scale) + shift
    ln_film<<<ROWS, 256, 0, stream>>>(x, se, h);
    // 3) qkv = h @ W_proj^T, fused per-head LN of q,k   (8192 x 3072 x 1024)
    gemm_bt<false, false, false, false, false, true><<<dim3(ROWS / 128, 3072 / 128), 256, 0, stream>>>(
        h, wprj_bf, nullptr, nullptr, qkv, ROWS, 3072, 1024,
        e0, e1, e2, e3, e4);
    // 4) attention -> o (B,N,C)
    if (use_flash) {
        vtrans<<<dim3(B_ * H_, N_ / 64), 256, 0, stream>>>(qkv, vT);
        flash_attn<<<dim3(B_ * H_, N_ / 256), 1024, 0, stream>>>(qkv, vT, o);
    } else {
        attn_simple<<<dim3(B_ * H_, N_ / 128), 256, 0, stream>>>(qkv, o);
    }
    // 5) out = o + o @ W_out^T             (8192 x 1024 x 1024)
    gemm_bt<false, true, false, true, true, false><<<dim3(ROWS / 128, 1024 / 128), 256, 0, stream>>>(
        o, W_out, nullptr, o, d_out, ROWS, 1024, 1024,
        e0, e1, e2, e3, e4);
}

// Round 11
// 559.174 us; speedup vs baseline: 1.0674x; 1.0674x over previous
//
#include <hip/hip_runtime.h>

#define B_ 4
#define N_ 2048
#define C_ 1024
#define H_ 16
#define D_ 64
#define ROWS (B_ * N_)   // 8192

typedef __bf16 bf16x8 __attribute__((ext_vector_type(8)));
typedef float f32x4 __attribute__((ext_vector_type(4)));
typedef unsigned short ushort_t;

__device__ inline float b2f(ushort_t u) {
    union { unsigned int i; float f; } v; v.i = ((unsigned int)u) << 16; return v.f;
}
// round-to-nearest-even f32 -> bf16
__device__ inline ushort_t f2b(float f) {
    union { float f; unsigned int i; } v; v.f = f;
    unsigned int r = v.i + 0x7fffu + ((v.i >> 16) & 1u);
    return (ushort_t)(r >> 16);
}

// Runtime dtype detector: f32 arrays show huge bf16 exponents in even
// half-words; bf16 arrays of sane magnitude never do.
__device__ inline bool detect_f32(const ushort_t* u) {
    int huge = 0;
#pragma unroll
    for (int i = 0; i < 64; ++i) {
        int ex = (u[2 * i] >> 7) & 0xFF;
        huge |= (ex >= 0xC0) ? 1 : 0;
    }
    return huge != 0;
}

// ---------------------------------------------------------------------------
// Dtype hoist: convert an f32 (or copy a bf16) array to bf16 once, so GEMM
// staging runs the cheap bf16 path instead of per-tile f32->bf16 conversion.
// (Round-9 win: -124us total.)
// ---------------------------------------------------------------------------
__global__ __launch_bounds__(256) void cvt_bf16(
    const void* __restrict__ src, ushort_t* __restrict__ dst, int n_elts)
{
    const bool s32 = detect_f32((const ushort_t*)src);
    const int start = (blockIdx.x * 256 + threadIdx.x) * 8;
    const int stride = gridDim.x * 256 * 8;
    if (s32) {
        const float* s = (const float*)src;
        for (int i = start; i < n_elts; i += stride) {
            float4 a = *(const float4*)(s + i);
            float4 b = *(const float4*)(s + i + 4);
            ushort4 w0, w1;
            w0.x = f2b(a.x); w0.y = f2b(a.y); w0.z = f2b(a.z); w0.w = f2b(a.w);
            w1.x = f2b(b.x); w1.y = f2b(b.y); w1.z = f2b(b.z); w1.w = f2b(b.w);
            *(ushort4*)(dst + i)     = w0;
            *(ushort4*)(dst + i + 4) = w1;
        }
    } else {
        const ushort_t* s = (const ushort_t*)src;
        for (int i = start; i < n_elts; i += stride)
            *(uint4*)(dst + i) = *(const uint4*)(s + i);
    }
}

// ---------------------------------------------------------------------------
// GEMM: C[M,N] = A[M,K] * B[N,K]^T (+ bias[N]) (+ resid[M,N]).
// 128x128 tile, BK=32, 4 waves (2x2), each wave 64x64 = 4x4 subtiles.
// (round-4 proven inner loop. Round-5 explicit double-buffer REGRESSED.
//  Round-10 XCD swizzle REGRESSED ~29us: working set is L3-resident, the
//  swizzle only pays when HBM-bound — guide m160 regime gate. Reverted.)
// LN_QK: fused per-head (64-col) LayerNorm of the f32 accumulators in the
// epilogue (wave's 64-col span == one head). OUT_DYN: f32 out iff all five
// external inputs are f32.
// ---------------------------------------------------------------------------
template<bool HAS_BIAS, bool HAS_RES, bool A_EXT, bool B_EXT, bool OUT_DYN, bool LN_QK>
__global__ __launch_bounds__(256) void gemm_bt(
    const void* __restrict__ A,
    const void* __restrict__ Bm,
    const ushort_t* __restrict__ bias,
    const ushort_t* __restrict__ resid,
    void* __restrict__ Cc,
    int M, int N, int K,
    const ushort_t* e0, const ushort_t* e1, const ushort_t* e2,
    const ushort_t* e3, const ushort_t* e4)
{
    const bool a32 = A_EXT ? detect_f32((const ushort_t*)A)  : false;
    const bool b32 = B_EXT ? detect_f32((const ushort_t*)Bm) : false;
    bool out32 = false;
    if constexpr (OUT_DYN)
        out32 = detect_f32(e0) && detect_f32(e1) && detect_f32(e2) &&
                detect_f32(e3) && detect_f32(e4);

    __shared__ __align__(16) ushort_t As[128][32];
    __shared__ __align__(16) ushort_t Bs[128][32];
    const int tid  = threadIdx.x;
    const int wave = tid >> 6, lane = tid & 63;
    const int lo = lane & 15, hi = lane >> 4;
    const int bm = blockIdx.x * 128, bn = blockIdx.y * 128;
    const int wm = (wave & 1) * 64,  wn = (wave >> 1) * 64;

    f32x4 acc[4][4] = {};

    for (int k0 = 0; k0 < K; k0 += 32) {
        if (a32) {
            const float* Af = (const float*)A;
#pragma unroll
            for (int i = 0; i < 4; ++i) {
                int c = tid + i * 256;
                int r = c >> 3, c4 = (c & 7) * 4;
                float4 v = *(const float4*)(Af + (size_t)(bm + r) * K + k0 + c4);
                ushort4 w; w.x = f2b(v.x); w.y = f2b(v.y); w.z = f2b(v.z); w.w = f2b(v.w);
                *(ushort4*)(&As[r][c4]) = w;
            }
        } else {
            const ushort_t* Ab = (const ushort_t*)A;
#pragma unroll
            for (int i = 0; i < 2; ++i) {
                int c = tid + i * 256;
                int r = c >> 2, c8 = (c & 3) * 8;
                *(uint4*)(&As[r][c8]) = *(const uint4*)(Ab + (size_t)(bm + r) * K + k0 + c8);
            }
        }
        if (b32) {
            const float* Bf = (const float*)Bm;
#pragma unroll
            for (int i = 0; i < 4; ++i) {
                int c = tid + i * 256;
                int r = c >> 3, c4 = (c & 7) * 4;
                float4 v = *(const float4*)(Bf + (size_t)(bn + r) * K + k0 + c4);
                ushort4 w; w.x = f2b(v.x); w.y = f2b(v.y); w.z = f2b(v.z); w.w = f2b(v.w);
                *(ushort4*)(&Bs[r][c4]) = w;
            }
        } else {
            const ushort_t* Bb = (const ushort_t*)Bm;
#pragma unroll
            for (int i = 0; i < 2; ++i) {
                int c = tid + i * 256;
                int r = c >> 2, c8 = (c & 3) * 8;
                *(uint4*)(&Bs[r][c8]) = *(const uint4*)(Bb + (size_t)(bn + r) * K + k0 + c8);
            }
        }
        __syncthreads();

        bf16x8 af[4], bfr[4];
#pragma unroll
        for (int i = 0; i < 4; ++i) af[i]  = *(const bf16x8*)(&As[wm + i * 16 + lo][hi * 8]);
#pragma unroll
        for (int j = 0; j < 4; ++j) bfr[j] = *(const bf16x8*)(&Bs[wn + j * 16 + lo][hi * 8]);
#pragma unroll
        for (int i = 0; i < 4; ++i)
#pragma unroll
            for (int j = 0; j < 4; ++j)
                acc[i][j] = __builtin_amdgcn_mfma_f32_16x16x32_bf16(af[i], bfr[j], acc[i][j], 0, 0, 0);
        __syncthreads();
    }

    if constexpr (LN_QK) {
        // per-head LN of q,k output columns (col0 = bn+wn, 64-aligned = 1 head)
        if (bn + wn < 2 * C_) {
#pragma unroll
            for (int i = 0; i < 4; ++i) {
#pragma unroll
                for (int r = 0; r < 4; ++r) {
                    float s = 0.0f, sq = 0.0f;
#pragma unroll
                    for (int j = 0; j < 4; ++j) {
                        float v = acc[i][j][r];
                        s += v; sq += v * v;
                    }
#pragma unroll
                    for (int off = 1; off < 16; off <<= 1) {
                        s  += __shfl_xor(s, off, 16);
                        sq += __shfl_xor(sq, off, 16);
                    }
                    const float mu   = s * (1.0f / 64.0f);
                    const float var  = sq * (1.0f / 64.0f) - mu * mu;
                    const float rstd = rsqrtf(var + 1e-5f);
#pragma unroll
                    for (int j = 0; j < 4; ++j)
                        acc[i][j][r] = (acc[i][j][r] - mu) * rstd;
                }
            }
        }
    }

#pragma unroll
    for (int i = 0; i < 4; ++i) {
#pragma unroll
        for (int j = 0; j < 4; ++j) {
            const int n = bn + wn + j * 16 + lo;
            float bv = HAS_BIAS ? b2f(bias[n]) : 0.0f;
#pragma unroll
            for (int r = 0; r < 4; ++r) {
                const int m = bm + wm + i * 16 + hi * 4 + r;
                float v = acc[i][j][r] + bv;
                if (HAS_RES) v += b2f(resid[(size_t)m * N + n]);
                if (OUT_DYN && out32) ((float*)Cc)[(size_t)m * N + n] = v;
                else                  ((ushort_t*)Cc)[(size_t)m * N + n] = f2b(v);
            }
        }
    }
}

// ---------------------------------------------------------------------------
// Fused LayerNorm(x) + FiLM: h = ln(x) * (1 + scale) + shift.
// ---------------------------------------------------------------------------
__global__ __launch_bounds__(256) void ln_film(
    const void* __restrict__ x,
    const ushort_t* __restrict__ se,
    ushort_t* __restrict__ h)
{
    const bool x32 = detect_f32((const ushort_t*)x);
    const int row = blockIdx.x;
    const int t = threadIdx.x;
    const int wave = t >> 6, lane = t & 63;

    float f0, f1, f2, f3;
    if (x32) {
        float4 v = *(const float4*)((const float*)x + (size_t)row * C_ + t * 4);
        f0 = v.x; f1 = v.y; f2 = v.z; f3 = v.w;
    } else {
        ushort4 v = *(const ushort4*)((const ushort_t*)x + (size_t)row * C_ + t * 4);
        f0 = b2f(v.x); f1 = b2f(v.y); f2 = b2f(v.z); f3 = b2f(v.w);
    }
    float s  = f0 + f1 + f2 + f3;
    float sq = f0 * f0 + f1 * f1 + f2 * f2 + f3 * f3;
#pragma unroll
    for (int off = 32; off >= 1; off >>= 1) {
        s  += __shfl_xor(s, off);
        sq += __shfl_xor(sq, off);
    }
    __shared__ float red[8];
    if (lane == 0) { red[wave] = s; red[4 + wave] = sq; }
    __syncthreads();
    s  = red[0] + red[1] + red[2] + red[3];
    sq = red[4] + red[5] + red[6] + red[7];
    const float mu   = s * (1.0f / C_);
    const float var  = sq * (1.0f / C_) - mu * mu;
    const float rstd = rsqrtf(var + 1e-5f);

    const ushort_t* ser = se + (size_t)row * (2 * C_);
    ushort4 sc = *(const ushort4*)(ser + t * 4);
    ushort4 sh = *(const ushort4*)(ser + C_ + t * 4);
    ushort4 out;
    out.x = f2b((f0 - mu) * rstd * (1.0f + b2f(sc.x)) + b2f(sh.x));
    out.y = f2b((f1 - mu) * rstd * (1.0f + b2f(sc.y)) + b2f(sh.y));
    out.z = f2b((f2 - mu) * rstd * (1.0f + b2f(sc.z)) + b2f(sh.z));
    out.w = f2b((f3 - mu) * rstd * (1.0f + b2f(sc.w)) + b2f(sh.w));
    *(ushort4*)(h + (size_t)row * C_ + t * 4) = out;
}

// ---------------------------------------------------------------------------
// V transpose: qkv (B,N,3,H,D) v-section -> vT (B,H,D,N). Coalesced both
// ways via LDS 64x64 tile. Grid: (B*H, N/64), 256 threads.
// ---------------------------------------------------------------------------
__global__ __launch_bounds__(256) void vtrans(
    const ushort_t* __restrict__ qkv,
    ushort_t* __restrict__ vT)
{
    const int bh = blockIdx.x, b = bh >> 4, hh = bh & 15;
    const int n0 = blockIdx.y * 64;
    const int t = threadIdx.x;
    __shared__ ushort_t Vs[64][65];

    const int r = t >> 2, c0 = (t & 3) * 16;   // row 0..63, col chunk of 16
    const ushort_t* src = qkv + (size_t)(b * N_ + n0 + r) * (3 * C_) + 2 * C_ + hh * D_;
#pragma unroll
    for (int i = 0; i < 16; ++i) Vs[r][c0 + i] = src[c0 + i];
    __syncthreads();
    // write rows of vT: thread t -> d = t>>2, n chunk (t&3)*16
    const int d = t >> 2, j0 = (t & 3) * 16;
    ushort_t* dst = vT + ((size_t)bh * D_ + d) * N_ + n0;
#pragma unroll
    for (int i = 0; i < 16; ++i) dst[j0 + i] = Vs[j0 + i][d];
}

// ---------------------------------------------------------------------------
// Flash attention v8 (8-wave, SINGLE-buffer K/V). Grid: (B*H, N/128).
// 512 threads = 8 waves, 16 q-rows each. Key change vs v6: the T14 staged
// registers ARE the second buffer, so the LDS double-buffer was redundant.
// Single K/V buffer (16KB) + reg-held next tile + two barriers per tile
// (read-drain, write-publish). LDS 34KB -> 4 blocks/CU = 32 waves (100%
// ceiling; v6's 51KB allowed only 3 blocks = 41% measured), and grid 1024
// = exactly 4 blocks/CU -> no tail. XOR-swizzled K/V LDS (chunk ^= row&7).
// Softmax exp2-domain with defer-max (THR=11); P via wave-private padded
// LDS slice (intra-wave lgkmcnt fence only).
// ---------------------------------------------------------------------------
__global__ __launch_bounds__(512) void flash_attn(
    const ushort_t* __restrict__ qkv,
    const ushort_t* __restrict__ vT,
    ushort_t* __restrict__ o)
{
    const int bh = blockIdx.x, b = bh >> 4, hh = bh & 15;
    const int qb = blockIdx.y;
    const int tid = threadIdx.x;
    const int wave = tid >> 6, lane = tid & 63;
    const int lo = lane & 15, hi = lane >> 4;

    __shared__ __align__(16) ushort_t Ks[64 * 64];      // 8KB, swizzled chunks
    __shared__ __align__(16) ushort_t Vsh[64 * 64];     // 8KB
    __shared__ __align__(16) ushort_t Pl[8][16][72];    // wave-private, padded

    // staging slot geometry: slot s (0..511) = one 16B chunk; row r=s>>3, chunk c=s&7
    const int sr = tid >> 3, sc = tid & 7;
    // swizzled LDS ushort offset for this thread's slot
    const int lsw = sr * 64 + ((sc ^ (sr & 7)) * 8);

    const int qrow = qb * 128 + wave * 16;
    // Q fragment (A-layout): row = qrow+lo, cols hi*8.. and 32+hi*8..
    const ushort_t* qp = qkv + (size_t)(b * N_ + qrow + lo) * (3 * C_) + hh * D_;
    const bf16x8 a0 = *(const bf16x8*)(qp + hi * 8);
    const bf16x8 a1 = *(const bf16x8*)(qp + 32 + hi * 8);

    // staging bases: K rows are keys (stride 3C); V rows are d (stride N)
    const ushort_t* Kg = qkv + (size_t)b * N_ * (3 * C_) + C_ + hh * D_;
    const ushort_t* Vg = vT + (size_t)bh * D_ * N_;

    f32x4 accO[4] = {};
    float m_r[4], l_r[4];
#pragma unroll
    for (int r = 0; r < 4; ++r) { m_r[r] = -1e30f; l_r[r] = 0.0f; }
    const f32x4 zero = {0.f, 0.f, 0.f, 0.f};
    const float SC = 0.125f * 1.44269504f;   // 1/sqrt(64) * log2(e)

    // swizzled read chunk offsets (in ushorts): chunks hi and 4+hi of a row,
    // row&7 == lo&7 for every fragment row this lane touches
    const int q0 = (hi ^ (lo & 7)) * 8;
    const int q1 = ((4 + hi) ^ (lo & 7)) * 8;

    // ---- prologue: stage tile 0 ----
    uint4 kst, vst;
    kst = *(const uint4*)(Kg + (size_t)sr * (3 * C_) + sc * 8);
    vst = *(const uint4*)(Vg + (size_t)sr * N_ + sc * 8);
    *(uint4*)(&Ks[lsw])  = kst;
    *(uint4*)(&Vsh[lsw]) = vst;
    __syncthreads();

    for (int kt = 0; kt < N_; kt += 64) {
        // T14 issue-early: launch tile t+1 global loads before compute
        const bool more = (kt + 64 < N_);
        if (more) {
            kst = *(const uint4*)(Kg + (size_t)(kt + 64 + sr) * (3 * C_) + sc * 8);
            vst = *(const uint4*)(Vg + (size_t)sr * N_ + (kt + 64) + sc * 8);
        }
        __builtin_amdgcn_sched_barrier(0);   // keep load issue above compute

        // ---- QK^T for 4 groups of 16 keys ----
        f32x4 S[4];
#pragma unroll
        for (int g = 0; g < 4; ++g) {
            const int R = g * 16 + lo;
            bf16x8 kl = *(const bf16x8*)(Ks + R * 64 + q0);
            bf16x8 kh = *(const bf16x8*)(Ks + R * 64 + q1);
            f32x4 s0 = __builtin_amdgcn_mfma_f32_16x16x32_bf16(a0, kl, zero, 0, 0, 0);
            S[g]     = __builtin_amdgcn_mfma_f32_16x16x32_bf16(a1, kh, s0,   0, 0, 0);
        }

        // ---- online softmax, exp2 domain ----
        float sv[4][4], pmax[4];
#pragma unroll
        for (int r = 0; r < 4; ++r) {
            float s0 = S[0][r] * SC, s1 = S[1][r] * SC;
            float s2 = S[2][r] * SC, s3 = S[3][r] * SC;
            sv[r][0] = s0; sv[r][1] = s1; sv[r][2] = s2; sv[r][3] = s3;
            float mx = fmaxf(fmaxf(s0, s1), fmaxf(s2, s3));
#pragma unroll
            for (int off = 1; off < 16; off <<= 1) mx = fmaxf(mx, __shfl_xor(mx, off, 16));
            pmax[r] = mx;
        }
        // defer-max: only rescale when some row's max grew past THR=11 (log2)
        int needi = 0;
#pragma unroll
        for (int r = 0; r < 4; ++r) needi |= (pmax[r] > m_r[r] + 11.0f) ? 1 : 0;
        if (__any(needi)) {
#pragma unroll
            for (int r = 0; r < 4; ++r) {
                float mnew  = fmaxf(m_r[r], pmax[r]);
                float alpha = __builtin_amdgcn_exp2f(m_r[r] - mnew);
                m_r[r] = mnew;
                l_r[r] *= alpha;
#pragma unroll
                for (int ds = 0; ds < 4; ++ds) accO[ds][r] *= alpha;
            }
        }
#pragma unroll
        for (int r = 0; r < 4; ++r) {
            float rs = 0.0f;
#pragma unroll
            for (int g = 0; g < 4; ++g) {
                float pv = __builtin_amdgcn_exp2f(sv[r][g] - m_r[r]);
                Pl[wave][hi * 4 + r][g * 16 + lo] = f2b(pv);
                rs += pv;
            }
#pragma unroll
            for (int off = 1; off < 16; off <<= 1) rs += __shfl_xor(rs, off, 16);
            l_r[r] += rs;
        }

        // intra-wave LDS RAW fence for Pl (wave-private slice, no barrier)
        asm volatile("s_waitcnt lgkmcnt(0)" ::: "memory");
        __builtin_amdgcn_sched_barrier(0);

        // ---- PV: P (16x64) x V^T tile (64d x 64k) ----
        bf16x8 pf0 = *(const bf16x8*)(&Pl[wave][lo][hi * 8]);        // keys 0..31
        bf16x8 pf1 = *(const bf16x8*)(&Pl[wave][lo][32 + hi * 8]);   // keys 32..63
#pragma unroll
        for (int ds = 0; ds < 4; ++ds) {
            const int R = ds * 16 + lo;
            bf16x8 vf0 = *(const bf16x8*)(Vsh + R * 64 + q0);
            bf16x8 vf1 = *(const bf16x8*)(Vsh + R * 64 + q1);
            accO[ds] = __builtin_amdgcn_mfma_f32_16x16x32_bf16(pf0, vf0, accO[ds], 0, 0, 0);
            accO[ds] = __builtin_amdgcn_mfma_f32_16x16x32_bf16(pf1, vf1, accO[ds], 0, 0, 0);
        }

        // ---- write-late: overwrite the single buffer with the next tile ----
        if (more) {
            __syncthreads();                   // all waves done reading LDS
            *(uint4*)(&Ks[lsw])  = kst;
            *(uint4*)(&Vsh[lsw]) = vst;
            __syncthreads();                   // next tile visible to all
        }
    }

#pragma unroll
    for (int ds = 0; ds < 4; ++ds)
#pragma unroll
        for (int r = 0; r < 4; ++r) {
            const int row = qrow + hi * 4 + r;
            float val = accO[ds][r] / l_r[r];
            o[((size_t)(b * N_ + row)) * C_ + hh * D_ + ds * 16 + lo] = f2b(val);
        }
}

// ---------------------------------------------------------------------------
// Fallback simple attention (proven correct, slow) for small workspaces.
// ---------------------------------------------------------------------------
__global__ __launch_bounds__(256) void attn_simple(
    const ushort_t* __restrict__ qkv,
    ushort_t* __restrict__ o)
{
    const int bh = blockIdx.x, b = bh >> 4, hh = bh & 15;
    const int t = threadIdx.x, lane = t & 63, wave = t >> 6;
    __shared__ float sc[N_];
    __shared__ float qrow[D_];
    __shared__ float red[4];
    __shared__ float opart[4][D_];

    const size_t hbase = (size_t)b * N_ * (3 * C_) + (size_t)hh * D_;

    for (int qi = 0; qi < 128; ++qi) {
        const int qr = blockIdx.y * 128 + qi;
        if (t < 64) qrow[t] = b2f(qkv[hbase + (size_t)qr * (3 * C_) + t]);
        __syncthreads();

        float myS[8];
        float mymax = -1e30f;
#pragma unroll
        for (int jj = 0; jj < 8; ++jj) {
            const int j = t + jj * 256;
            const bf16x8* kr = (const bf16x8*)(qkv + hbase + (size_t)j * (3 * C_) + C_);
            float s = 0.0f;
#pragma unroll
            for (int c = 0; c < 8; ++c) {
                bf16x8 kv = kr[c];
#pragma unroll
                for (int e = 0; e < 8; ++e) s += qrow[c * 8 + e] * (float)kv[e];
            }
            s *= 0.125f;
            myS[jj] = s;
            mymax = fmaxf(mymax, s);
        }
#pragma unroll
        for (int off = 32; off >= 1; off >>= 1) mymax = fmaxf(mymax, __shfl_xor(mymax, off));
        if (lane == 0) red[wave] = mymax;
        __syncthreads();
        const float M = fmaxf(fmaxf(red[0], red[1]), fmaxf(red[2], red[3]));

        float mysum = 0.0f;
#pragma unroll
        for (int jj = 0; jj < 8; ++jj) {
            float p = __expf(myS[jj] - M);
            sc[t + jj * 256] = p;
            mysum += p;
        }
#pragma unroll
        for (int off = 32; off >= 1; off >>= 1) mysum += __shfl_xor(mysum, off);
        __syncthreads();
        if (lane == 0) red[wave] = mysum;
        __syncthreads();
        const float L = red[0] + red[1] + red[2] + red[3];

        float acc = 0.0f;
        const int d = lane;
        const ushort_t* vb = qkv + hbase + 2 * C_ + d;
        for (int j = wave * 512; j < wave * 512 + 512; ++j)
            acc += sc[j] * b2f(vb[(size_t)j * (3 * C_)]);
        opart[wave][d] = acc;
        __syncthreads();
        if (t < 64) {
            float val = (opart[0][t] + opart[1][t] + opart[2][t] + opart[3][t]) / L;
            o[((size_t)(b * N_ + qr)) * C_ + hh * D_ + t] = f2b(val);
        }
        __syncthreads();
    }
}

// ---------------------------------------------------------------------------
extern "C" void kernel_launch(void* const* d_in, const int* in_sizes, int n_in,
                              void* d_out, int out_size, void* d_ws, size_t ws_size,
                              hipStream_t stream)
{
    const void* x = nullptr; const void* emb = nullptr;
    const void* W_emb = nullptr; const void* b_emb = nullptr;
    const void* W_proj = nullptr; const void* W_out = nullptr;
    int big_seen = 0;
    for (int i = 0; i < n_in; ++i) {
        const int s = in_sizes[i];
        if      (s == ROWS * C_)   { if (big_seen++ == 0) x = d_in[i]; else emb = d_in[i]; }
        else if (s == 2 * C_ * C_) W_emb  = d_in[i];
        else if (s == 3 * C_ * C_) W_proj = d_in[i];
        else if (s == C_ * C_)     W_out  = d_in[i];
        else if (s == 2 * C_)      b_emb  = d_in[i];
    }

    // Workspace (80 MB budget), with dtype-hoisted bf16 copies:
    //   h        [0,16)    P2 -> P3
    //   se       [16,48)   P1 -> P2
    //   qkv      [16,64)   P3 (over dead se) -> P4
    //   o        [0,16)    P4 (over dead h)  -> P5
    //   vT       [64,80)   P4a -> P4b
    //   W_emb_bf [48,52)   P0 -> P1 (dead before qkv write at P3)
    //   emb_bf   [58,74)   P0 -> P1 (dead before vT write at P4a)
    //   W_proj_bf[74,80)   P0 -> P3 (clobbered by vT at P4a, already dead)
    char* ws = (char*)d_ws;
    const size_t MB = 1024 * 1024;
    ushort_t* h       = (ushort_t*)(ws);
    ushort_t* se      = (ushort_t*)(ws + 16 * MB);
    ushort_t* qkv     = (ushort_t*)(ws + 16 * MB);
    ushort_t* o       = (ushort_t*)(ws);
    ushort_t* vT      = (ushort_t*)(ws + 64 * MB);
    ushort_t* wemb_bf = (ushort_t*)(ws + 48 * MB);
    ushort_t* emb_bf  = (ushort_t*)(ws + 58 * MB);
    ushort_t* wprj_bf = (ushort_t*)(ws + 74 * MB);
    const bool use_flash = (ws_size >= 80 * MB);

    const ushort_t* e0 = (const ushort_t*)x;
    const ushort_t* e1 = (const ushort_t*)emb;
    const ushort_t* e2 = (const ushort_t*)W_emb;
    const ushort_t* e3 = (const ushort_t*)W_proj;
    const ushort_t* e4 = (const ushort_t*)W_out;

    // 0) hoist dtype conversion out of GEMM K-loops (f32 -> bf16 once)
    cvt_bf16<<<2048, 256, 0, stream>>>(emb,    emb_bf,  ROWS * C_);
    cvt_bf16<<<1024, 256, 0, stream>>>(W_emb,  wemb_bf, 2 * C_ * C_);
    cvt_bf16<<<1024, 256, 0, stream>>>(W_proj, wprj_bf, 3 * C_ * C_);

    // 1) se = emb @ W_emb^T + b_emb        (8192 x 2048 x 1024), all-bf16 path
    gemm_bt<true, false, false, false, false, false><<<dim3(ROWS / 128, 2048 / 128), 256, 0, stream>>>(
        emb_bf, wemb_bf, (const ushort_t*)b_emb, nullptr, se, ROWS, 2048, 1024,
        e0, e1, e2, e3, e4);
    // 2) h = ln(x) * (1 + scale) + shift
    ln_film<<<ROWS, 256, 0, stream>>>(x, se, h);
    // 3) qkv = h @ W_proj^T, fused per-head LN of q,k   (8192 x 3072 x 1024)
    gemm_bt<false, false, false, false, false, true><<<dim3(ROWS / 128, 3072 / 128), 256, 0, stream>>>(
        h, wprj_bf, nullptr, nullptr, qkv, ROWS, 3072, 1024,
        e0, e1, e2, e3, e4);
    // 4) attention -> o (B,N,C)
    if (use_flash) {
        vtrans<<<dim3(B_ * H_, N_ / 64), 256, 0, stream>>>(qkv, vT);
        flash_attn<<<dim3(B_ * H_, N_ / 128), 512, 0, stream>>>(qkv, vT, o);
    } else {
        attn_simple<<<dim3(B_ * H_, N_ / 128), 256, 0, stream>>>(qkv, o);
    }
    // 5) out = o + o @ W_out^T             (8192 x 1024 x 1024)
    gemm_bt<false, true, false, true, true, false><<<dim3(ROWS / 128, 1024 / 128), 256, 0, stream>>>(
        o, W_out, nullptr, o, d_out, ROWS, 1024, 1024,
        e0, e1, e2, e3, e4);
}

// Round 12
// 494.172 us; speedup vs baseline: 1.2078x; 1.1315x over previous
//
#include <hip/hip_runtime.h>

#define B_ 4
#define N_ 2048
#define C_ 1024
#define H_ 16
#define D_ 64
#define ROWS (B_ * N_)   // 8192

typedef __bf16 bf16x8 __attribute__((ext_vector_type(8)));
typedef float f32x4 __attribute__((ext_vector_type(4)));
typedef unsigned short ushort_t;

__device__ inline float b2f(ushort_t u) {
    union { unsigned int i; float f; } v; v.i = ((unsigned int)u) << 16; return v.f;
}
// round-to-nearest-even f32 -> bf16
__device__ inline ushort_t f2b(float f) {
    union { float f; unsigned int i; } v; v.f = f;
    unsigned int r = v.i + 0x7fffu + ((v.i >> 16) & 1u);
    return (ushort_t)(r >> 16);
}
// HW packed f32x2 -> bf16x2 (RNE on gfx950); no builtin, inline asm per guide T12
__device__ inline unsigned int cvtpk(float a, float b) {
    unsigned int r;
    asm("v_cvt_pk_bf16_f32 %0, %1, %2" : "=v"(r) : "v"(a), "v"(b));
    return r;
}

// Runtime dtype detector: f32 arrays show huge bf16 exponents in even
// half-words; bf16 arrays of sane magnitude never do.
__device__ inline bool detect_f32(const ushort_t* u) {
    int huge = 0;
#pragma unroll
    for (int i = 0; i < 64; ++i) {
        int ex = (u[2 * i] >> 7) & 0xFF;
        huge |= (ex >= 0xC0) ? 1 : 0;
    }
    return huge != 0;
}

// ---------------------------------------------------------------------------
// Dtype hoist: convert an f32 (or copy a bf16) array to bf16 once, so GEMM
// staging runs the cheap bf16 path instead of per-tile f32->bf16 conversion.
// (Round-9 win: -124us total.)
// ---------------------------------------------------------------------------
__global__ __launch_bounds__(256) void cvt_bf16(
    const void* __restrict__ src, ushort_t* __restrict__ dst, int n_elts)
{
    const bool s32 = detect_f32((const ushort_t*)src);
    const int start = (blockIdx.x * 256 + threadIdx.x) * 8;
    const int stride = gridDim.x * 256 * 8;
    if (s32) {
        const float* s = (const float*)src;
        for (int i = start; i < n_elts; i += stride) {
            float4 a = *(const float4*)(s + i);
            float4 b = *(const float4*)(s + i + 4);
            ushort4 w0, w1;
            w0.x = f2b(a.x); w0.y = f2b(a.y); w0.z = f2b(a.z); w0.w = f2b(a.w);
            w1.x = f2b(b.x); w1.y = f2b(b.y); w1.z = f2b(b.z); w1.w = f2b(b.w);
            *(ushort4*)(dst + i)     = w0;
            *(ushort4*)(dst + i + 4) = w1;
        }
    } else {
        const ushort_t* s = (const ushort_t*)src;
        for (int i = start; i < n_elts; i += stride)
            *(uint4*)(dst + i) = *(const uint4*)(s + i);
    }
}

// ---------------------------------------------------------------------------
// GEMM: C[M,N] = A[M,K] * B[N,K]^T (+ bias[N]) (+ resid[M,N]).
// 128x128 tile, BK=32, 4 waves (2x2), each wave 64x64 = 4x4 subtiles.
// (round-4 proven inner loop. Round-5 explicit double-buffer REGRESSED.
//  Round-10 XCD swizzle REGRESSED ~29us: working set is L3-resident —
//  guide m160 regime gate. Reverted.)
// LN_QK: fused per-head (64-col) LayerNorm of the f32 accumulators in the
// epilogue (wave's 64-col span == one head). OUT_DYN: f32 out iff all five
// external inputs are f32.
// ---------------------------------------------------------------------------
template<bool HAS_BIAS, bool HAS_RES, bool A_EXT, bool B_EXT, bool OUT_DYN, bool LN_QK>
__global__ __launch_bounds__(256) void gemm_bt(
    const void* __restrict__ A,
    const void* __restrict__ Bm,
    const ushort_t* __restrict__ bias,
    const ushort_t* __restrict__ resid,
    void* __restrict__ Cc,
    int M, int N, int K,
    const ushort_t* e0, const ushort_t* e1, const ushort_t* e2,
    const ushort_t* e3, const ushort_t* e4)
{
    const bool a32 = A_EXT ? detect_f32((const ushort_t*)A)  : false;
    const bool b32 = B_EXT ? detect_f32((const ushort_t*)Bm) : false;
    bool out32 = false;
    if constexpr (OUT_DYN)
        out32 = detect_f32(e0) && detect_f32(e1) && detect_f32(e2) &&
                detect_f32(e3) && detect_f32(e4);

    __shared__ __align__(16) ushort_t As[128][32];
    __shared__ __align__(16) ushort_t Bs[128][32];
    const int tid  = threadIdx.x;
    const int wave = tid >> 6, lane = tid & 63;
    const int lo = lane & 15, hi = lane >> 4;
    const int bm = blockIdx.x * 128, bn = blockIdx.y * 128;
    const int wm = (wave & 1) * 64,  wn = (wave >> 1) * 64;

    f32x4 acc[4][4] = {};

    for (int k0 = 0; k0 < K; k0 += 32) {
        if (a32) {
            const float* Af = (const float*)A;
#pragma unroll
            for (int i = 0; i < 4; ++i) {
                int c = tid + i * 256;
                int r = c >> 3, c4 = (c & 7) * 4;
                float4 v = *(const float4*)(Af + (size_t)(bm + r) * K + k0 + c4);
                ushort4 w; w.x = f2b(v.x); w.y = f2b(v.y); w.z = f2b(v.z); w.w = f2b(v.w);
                *(ushort4*)(&As[r][c4]) = w;
            }
        } else {
            const ushort_t* Ab = (const ushort_t*)A;
#pragma unroll
            for (int i = 0; i < 2; ++i) {
                int c = tid + i * 256;
                int r = c >> 2, c8 = (c & 3) * 8;
                *(uint4*)(&As[r][c8]) = *(const uint4*)(Ab + (size_t)(bm + r) * K + k0 + c8);
            }
        }
        if (b32) {
            const float* Bf = (const float*)Bm;
#pragma unroll
            for (int i = 0; i < 4; ++i) {
                int c = tid + i * 256;
                int r = c >> 3, c4 = (c & 7) * 4;
                float4 v = *(const float4*)(Bf + (size_t)(bn + r) * K + k0 + c4);
                ushort4 w; w.x = f2b(v.x); w.y = f2b(v.y); w.z = f2b(v.z); w.w = f2b(v.w);
                *(ushort4*)(&Bs[r][c4]) = w;
            }
        } else {
            const ushort_t* Bb = (const ushort_t*)Bm;
#pragma unroll
            for (int i = 0; i < 2; ++i) {
                int c = tid + i * 256;
                int r = c >> 2, c8 = (c & 3) * 8;
                *(uint4*)(&Bs[r][c8]) = *(const uint4*)(Bb + (size_t)(bn + r) * K + k0 + c8);
            }
        }
        __syncthreads();

        bf16x8 af[4], bfr[4];
#pragma unroll
        for (int i = 0; i < 4; ++i) af[i]  = *(const bf16x8*)(&As[wm + i * 16 + lo][hi * 8]);
#pragma unroll
        for (int j = 0; j < 4; ++j) bfr[j] = *(const bf16x8*)(&Bs[wn + j * 16 + lo][hi * 8]);
#pragma unroll
        for (int i = 0; i < 4; ++i)
#pragma unroll
            for (int j = 0; j < 4; ++j)
                acc[i][j] = __builtin_amdgcn_mfma_f32_16x16x32_bf16(af[i], bfr[j], acc[i][j], 0, 0, 0);
        __syncthreads();
    }

    if constexpr (LN_QK) {
        // per-head LN of q,k output columns (col0 = bn+wn, 64-aligned = 1 head)
        if (bn + wn < 2 * C_) {
#pragma unroll
            for (int i = 0; i < 4; ++i) {
#pragma unroll
                for (int r = 0; r < 4; ++r) {
                    float s = 0.0f, sq = 0.0f;
#pragma unroll
                    for (int j = 0; j < 4; ++j) {
                        float v = acc[i][j][r];
                        s += v; sq += v * v;
                    }
#pragma unroll
                    for (int off = 1; off < 16; off <<= 1) {
                        s  += __shfl_xor(s, off, 16);
                        sq += __shfl_xor(sq, off, 16);
                    }
                    const float mu   = s * (1.0f / 64.0f);
                    const float var  = sq * (1.0f / 64.0f) - mu * mu;
                    const float rstd = rsqrtf(var + 1e-5f);
#pragma unroll
                    for (int j = 0; j < 4; ++j)
                        acc[i][j][r] = (acc[i][j][r] - mu) * rstd;
                }
            }
        }
    }

#pragma unroll
    for (int i = 0; i < 4; ++i) {
#pragma unroll
        for (int j = 0; j < 4; ++j) {
            const int n = bn + wn + j * 16 + lo;
            float bv = HAS_BIAS ? b2f(bias[n]) : 0.0f;
#pragma unroll
            for (int r = 0; r < 4; ++r) {
                const int m = bm + wm + i * 16 + hi * 4 + r;
                float v = acc[i][j][r] + bv;
                if (HAS_RES) v += b2f(resid[(size_t)m * N + n]);
                if (OUT_DYN && out32) ((float*)Cc)[(size_t)m * N + n] = v;
                else                  ((ushort_t*)Cc)[(size_t)m * N + n] = f2b(v);
            }
        }
    }
}

// ---------------------------------------------------------------------------
// Fused LayerNorm(x) + FiLM: h = ln(x) * (1 + scale) + shift.
// ---------------------------------------------------------------------------
__global__ __launch_bounds__(256) void ln_film(
    const void* __restrict__ x,
    const ushort_t* __restrict__ se,
    ushort_t* __restrict__ h)
{
    const bool x32 = detect_f32((const ushort_t*)x);
    const int row = blockIdx.x;
    const int t = threadIdx.x;
    const int wave = t >> 6, lane = t & 63;

    float f0, f1, f2, f3;
    if (x32) {
        float4 v = *(const float4*)((const float*)x + (size_t)row * C_ + t * 4);
        f0 = v.x; f1 = v.y; f2 = v.z; f3 = v.w;
    } else {
        ushort4 v = *(const ushort4*)((const ushort_t*)x + (size_t)row * C_ + t * 4);
        f0 = b2f(v.x); f1 = b2f(v.y); f2 = b2f(v.z); f3 = b2f(v.w);
    }
    float s  = f0 + f1 + f2 + f3;
    float sq = f0 * f0 + f1 * f1 + f2 * f2 + f3 * f3;
#pragma unroll
    for (int off = 32; off >= 1; off >>= 1) {
        s  += __shfl_xor(s, off);
        sq += __shfl_xor(sq, off);
    }
    __shared__ float red[8];
    if (lane == 0) { red[wave] = s; red[4 + wave] = sq; }
    __syncthreads();
    s  = red[0] + red[1] + red[2] + red[3];
    sq = red[4] + red[5] + red[6] + red[7];
    const float mu   = s * (1.0f / C_);
    const float var  = sq * (1.0f / C_) - mu * mu;
    const float rstd = rsqrtf(var + 1e-5f);

    const ushort_t* ser = se + (size_t)row * (2 * C_);
    ushort4 sc = *(const ushort4*)(ser + t * 4);
    ushort4 sh = *(const ushort4*)(ser + C_ + t * 4);
    ushort4 out;
    out.x = f2b((f0 - mu) * rstd * (1.0f + b2f(sc.x)) + b2f(sh.x));
    out.y = f2b((f1 - mu) * rstd * (1.0f + b2f(sc.y)) + b2f(sh.y));
    out.z = f2b((f2 - mu) * rstd * (1.0f + b2f(sc.z)) + b2f(sh.z));
    out.w = f2b((f3 - mu) * rstd * (1.0f + b2f(sc.w)) + b2f(sh.w));
    *(ushort4*)(h + (size_t)row * C_ + t * 4) = out;
}

// ---------------------------------------------------------------------------
// V transpose: qkv (B,N,3,H,D) v-section -> vT (B,H,D,N). Coalesced both
// ways via LDS 64x64 tile. Grid: (B*H, N/64), 256 threads.
// ---------------------------------------------------------------------------
__global__ __launch_bounds__(256) void vtrans(
    const ushort_t* __restrict__ qkv,
    ushort_t* __restrict__ vT)
{
    const int bh = blockIdx.x, b = bh >> 4, hh = bh & 15;
    const int n0 = blockIdx.y * 64;
    const int t = threadIdx.x;
    __shared__ ushort_t Vs[64][65];

    const int r = t >> 2, c0 = (t & 3) * 16;   // row 0..63, col chunk of 16
    const ushort_t* src = qkv + (size_t)(b * N_ + n0 + r) * (3 * C_) + 2 * C_ + hh * D_;
#pragma unroll
    for (int i = 0; i < 16; ++i) Vs[r][c0 + i] = src[c0 + i];
    __syncthreads();
    // write rows of vT: thread t -> d = t>>2, n chunk (t&3)*16
    const int d = t >> 2, j0 = (t & 3) * 16;
    ushort_t* dst = vT + ((size_t)bh * D_ + d) * N_ + n0;
#pragma unroll
    for (int i = 0; i < 16; ++i) dst[j0 + i] = Vs[j0 + i][d];
}

// ---------------------------------------------------------------------------
// Flash attention v9 (8-wave, single-buffer, VALU-thinned softmax).
// Grid: (B*H, N/128). 512 threads = 8 waves, 16 q-rows each.
// Occupancy experiments (v6 3blk/41%, v7 2blk/45%, v8 4blk/40%) showed perf
// is INSENSITIVE to resident waves -> kernel is VALU-issue-bound on the
// per-tile softmax chain (~480 VALU cyc/tile vs ~80 MFMA). v9 thins it:
//  (1) SC scale folded into Q fragments once at load (kills 16 mults/tile)
//  (2) defer-max check on LANE-LOCAL max (row-max <= m+THR iff all lane
//      maxes are); full 16-lane reduce only inside the rare rescale branch
//  (3) lane-local l partial sums (alpha is row-uniform so rescale applies
//      to partials); single 16-lane reduce at epilogue
//  (4) v_cvt_pk_bf16_f32 (HW RNE) for P->bf16: 8 cvt_pk + 8 shifts replace
//      ~48 software-RNE ops
// Single K/V LDS buffer (34KB) + T14 reg-held next tile + 2 barriers/tile.
// XOR-swizzled K/V LDS (chunk ^= row&7). P via wave-private padded slice.
// ---------------------------------------------------------------------------
__global__ __launch_bounds__(512) void flash_attn(
    const ushort_t* __restrict__ qkv,
    const ushort_t* __restrict__ vT,
    ushort_t* __restrict__ o)
{
    const int bh = blockIdx.x, b = bh >> 4, hh = bh & 15;
    const int qb = blockIdx.y;
    const int tid = threadIdx.x;
    const int wave = tid >> 6, lane = tid & 63;
    const int lo = lane & 15, hi = lane >> 4;

    __shared__ __align__(16) ushort_t Ks[64 * 64];      // 8KB, swizzled chunks
    __shared__ __align__(16) ushort_t Vsh[64 * 64];     // 8KB
    __shared__ __align__(16) ushort_t Pl[8][16][72];    // wave-private, padded

    // staging slot geometry: slot s (0..511) = one 16B chunk; row r=s>>3, chunk c=s&7
    const int sr = tid >> 3, sc = tid & 7;
    const int lsw = sr * 64 + ((sc ^ (sr & 7)) * 8);    // swizzled ushort offset

    const int qrow = qb * 128 + wave * 16;
    // Q fragment (A-layout), pre-scaled by SC = 1/sqrt(64)*log2(e) so QK^T
    // lands directly in the exp2 domain (VALU cut #1).
    const float SC = 0.125f * 1.44269504f;
    const ushort_t* qp = qkv + (size_t)(b * N_ + qrow + lo) * (3 * C_) + hh * D_;
    bf16x8 a0 = *(const bf16x8*)(qp + hi * 8);
    bf16x8 a1 = *(const bf16x8*)(qp + 32 + hi * 8);
#pragma unroll
    for (int i = 0; i < 8; ++i) {
        a0[i] = (__bf16)((float)a0[i] * SC);
        a1[i] = (__bf16)((float)a1[i] * SC);
    }

    // staging bases: K rows are keys (stride 3C); V rows are d (stride N)
    const ushort_t* Kg = qkv + (size_t)b * N_ * (3 * C_) + C_ + hh * D_;
    const ushort_t* Vg = vT + (size_t)bh * D_ * N_;

    f32x4 accO[4] = {};
    float m_r[4], l_p[4];                      // running max, LANE-LOCAL l partials
#pragma unroll
    for (int r = 0; r < 4; ++r) { m_r[r] = -1e30f; l_p[r] = 0.0f; }
    const f32x4 zero = {0.f, 0.f, 0.f, 0.f};

    // swizzled read chunk offsets (in ushorts): chunks hi and 4+hi of a row,
    // row&7 == lo&7 for every fragment row this lane touches
    const int q0 = (hi ^ (lo & 7)) * 8;
    const int q1 = ((4 + hi) ^ (lo & 7)) * 8;

    // ---- prologue: stage tile 0 ----
    uint4 kst, vst;
    kst = *(const uint4*)(Kg + (size_t)sr * (3 * C_) + sc * 8);
    vst = *(const uint4*)(Vg + (size_t)sr * N_ + sc * 8);
    *(uint4*)(&Ks[lsw])  = kst;
    *(uint4*)(&Vsh[lsw]) = vst;
    __syncthreads();

    for (int kt = 0; kt < N_; kt += 64) {
        // T14 issue-early: launch tile t+1 global loads before compute
        const bool more = (kt + 64 < N_);
        if (more) {
            kst = *(const uint4*)(Kg + (size_t)(kt + 64 + sr) * (3 * C_) + sc * 8);
            vst = *(const uint4*)(Vg + (size_t)sr * N_ + (kt + 64) + sc * 8);
        }
        __builtin_amdgcn_sched_barrier(0);   // keep load issue above compute

        // ---- QK^T for 4 groups of 16 keys (already exp2-domain via Q scale) ----
        f32x4 S[4];
#pragma unroll
        for (int g = 0; g < 4; ++g) {
            const int R = g * 16 + lo;
            bf16x8 kl = *(const bf16x8*)(Ks + R * 64 + q0);
            bf16x8 kh = *(const bf16x8*)(Ks + R * 64 + q1);
            f32x4 s0 = __builtin_amdgcn_mfma_f32_16x16x32_bf16(a0, kl, zero, 0, 0, 0);
            S[g]     = __builtin_amdgcn_mfma_f32_16x16x32_bf16(a1, kh, s0,   0, 0, 0);
        }

        // ---- online softmax: lane-local defer-max (VALU cuts #2/#3) ----
        float mx[4];
        int needi = 0;
#pragma unroll
        for (int r = 0; r < 4; ++r) {
            mx[r] = fmaxf(fmaxf(S[0][r], S[1][r]), fmaxf(S[2][r], S[3][r]));
            needi |= (mx[r] > m_r[r] + 11.0f) ? 1 : 0;
        }
        if (__any(needi)) {
            // rare: full row-max reduce + rescale (alpha row-uniform)
#pragma unroll
            for (int r = 0; r < 4; ++r) {
                float fm = mx[r];
#pragma unroll
                for (int off = 1; off < 16; off <<= 1) fm = fmaxf(fm, __shfl_xor(fm, off, 16));
                float mnew  = fmaxf(m_r[r], fm);
                float alpha = __builtin_amdgcn_exp2f(m_r[r] - mnew);
                m_r[r] = mnew;
                l_p[r] *= alpha;
#pragma unroll
                for (int ds = 0; ds < 4; ++ds) accO[ds][r] *= alpha;
            }
        }
#pragma unroll
        for (int r = 0; r < 4; ++r) {
            float p0 = __builtin_amdgcn_exp2f(S[0][r] - m_r[r]);
            float p1 = __builtin_amdgcn_exp2f(S[1][r] - m_r[r]);
            float p2 = __builtin_amdgcn_exp2f(S[2][r] - m_r[r]);
            float p3 = __builtin_amdgcn_exp2f(S[3][r] - m_r[r]);
            unsigned int c01 = cvtpk(p0, p1);          // VALU cut #4
            unsigned int c23 = cvtpk(p2, p3);
            ushort_t* prow = &Pl[wave][hi * 4 + r][lo];
            prow[0]  = (ushort_t)(c01 & 0xffffu);
            prow[16] = (ushort_t)(c01 >> 16);
            prow[32] = (ushort_t)(c23 & 0xffffu);
            prow[48] = (ushort_t)(c23 >> 16);
            l_p[r] += (p0 + p1) + (p2 + p3);           // lane-local partial
        }

        // intra-wave LDS RAW fence for Pl (wave-private slice, no barrier)
        asm volatile("s_waitcnt lgkmcnt(0)" ::: "memory");
        __builtin_amdgcn_sched_barrier(0);

        // ---- PV: P (16x64) x V^T tile (64d x 64k) ----
        bf16x8 pf0 = *(const bf16x8*)(&Pl[wave][lo][hi * 8]);        // keys 0..31
        bf16x8 pf1 = *(const bf16x8*)(&Pl[wave][lo][32 + hi * 8]);   // keys 32..63
#pragma unroll
        for (int ds = 0; ds < 4; ++ds) {
            const int R = ds * 16 + lo;
            bf16x8 vf0 = *(const bf16x8*)(Vsh + R * 64 + q0);
            bf16x8 vf1 = *(const bf16x8*)(Vsh + R * 64 + q1);
            accO[ds] = __builtin_amdgcn_mfma_f32_16x16x32_bf16(pf0, vf0, accO[ds], 0, 0, 0);
            accO[ds] = __builtin_amdgcn_mfma_f32_16x16x32_bf16(pf1, vf1, accO[ds], 0, 0, 0);
        }

        // ---- write-late: overwrite the single buffer with the next tile ----
        if (more) {
            __syncthreads();                   // all waves done reading LDS
            *(uint4*)(&Ks[lsw])  = kst;
            *(uint4*)(&Vsh[lsw]) = vst;
            __syncthreads();                   // next tile visible to all
        }
    }

    // epilogue: reduce the lane-local l partials once (VALU cut #3)
    float l_r[4];
#pragma unroll
    for (int r = 0; r < 4; ++r) {
        float l = l_p[r];
#pragma unroll
        for (int off = 1; off < 16; off <<= 1) l += __shfl_xor(l, off, 16);
        l_r[r] = l;
    }

#pragma unroll
    for (int ds = 0; ds < 4; ++ds)
#pragma unroll
        for (int r = 0; r < 4; ++r) {
            const int row = qrow + hi * 4 + r;
            float val = accO[ds][r] / l_r[r];
            o[((size_t)(b * N_ + row)) * C_ + hh * D_ + ds * 16 + lo] = f2b(val);
        }
}

// ---------------------------------------------------------------------------
// Fallback simple attention (proven correct, slow) for small workspaces.
// ---------------------------------------------------------------------------
__global__ __launch_bounds__(256) void attn_simple(
    const ushort_t* __restrict__ qkv,
    ushort_t* __restrict__ o)
{
    const int bh = blockIdx.x, b = bh >> 4, hh = bh & 15;
    const int t = threadIdx.x, lane = t & 63, wave = t >> 6;
    __shared__ float sc[N_];
    __shared__ float qrow[D_];
    __shared__ float red[4];
    __shared__ float opart[4][D_];

    const size_t hbase = (size_t)b * N_ * (3 * C_) + (size_t)hh * D_;

    for (int qi = 0; qi < 128; ++qi) {
        const int qr = blockIdx.y * 128 + qi;
        if (t < 64) qrow[t] = b2f(qkv[hbase + (size_t)qr * (3 * C_) + t]);
        __syncthreads();

        float myS[8];
        float mymax = -1e30f;
#pragma unroll
        for (int jj = 0; jj < 8; ++jj) {
            const int j = t + jj * 256;
            const bf16x8* kr = (const bf16x8*)(qkv + hbase + (size_t)j * (3 * C_) + C_);
            float s = 0.0f;
#pragma unroll
            for (int c = 0; c < 8; ++c) {
                bf16x8 kv = kr[c];
#pragma unroll
                for (int e = 0; e < 8; ++e) s += qrow[c * 8 + e] * (float)kv[e];
            }
            s *= 0.125f;
            myS[jj] = s;
            mymax = fmaxf(mymax, s);
        }
#pragma unroll
        for (int off = 32; off >= 1; off >>= 1) mymax = fmaxf(mymax, __shfl_xor(mymax, off));
        if (lane == 0) red[wave] = mymax;
        __syncthreads();
        const float M = fmaxf(fmaxf(red[0], red[1]), fmaxf(red[2], red[3]));

        float mysum = 0.0f;
#pragma unroll
        for (int jj = 0; jj < 8; ++jj) {
            float p = __expf(myS[jj] - M);
            sc[t + jj * 256] = p;
            mysum += p;
        }
#pragma unroll
        for (int off = 32; off >= 1; off >>= 1) mysum += __shfl_xor(mysum, off);
        __syncthreads();
        if (lane == 0) red[wave] = mysum;
        __syncthreads();
        const float L = red[0] + red[1] + red[2] + red[3];

        float acc = 0.0f;
        const int d = lane;
        const ushort_t* vb = qkv + hbase + 2 * C_ + d;
        for (int j = wave * 512; j < wave * 512 + 512; ++j)
            acc += sc[j] * b2f(vb[(size_t)j * (3 * C_)]);
        opart[wave][d] = acc;
        __syncthreads();
        if (t < 64) {
            float val = (opart[0][t] + opart[1][t] + opart[2][t] + opart[3][t]) / L;
            o[((size_t)(b * N_ + qr)) * C_ + hh * D_ + t] = f2b(val);
        }
        __syncthreads();
    }
}

// ---------------------------------------------------------------------------
extern "C" void kernel_launch(void* const* d_in, const int* in_sizes, int n_in,
                              void* d_out, int out_size, void* d_ws, size_t ws_size,
                              hipStream_t stream)
{
    const void* x = nullptr; const void* emb = nullptr;
    const void* W_emb = nullptr; const void* b_emb = nullptr;
    const void* W_proj = nullptr; const void* W_out = nullptr;
    int big_seen = 0;
    for (int i = 0; i < n_in; ++i) {
        const int s = in_sizes[i];
        if      (s == ROWS * C_)   { if (big_seen++ == 0) x = d_in[i]; else emb = d_in[i]; }
        else if (s == 2 * C_ * C_) W_emb  = d_in[i];
        else if (s == 3 * C_ * C_) W_proj = d_in[i];
        else if (s == C_ * C_)     W_out  = d_in[i];
        else if (s == 2 * C_)      b_emb  = d_in[i];
    }

    // Workspace (80 MB budget), with dtype-hoisted bf16 copies:
    //   h        [0,16)    P2 -> P3
    //   se       [16,48)   P1 -> P2
    //   qkv      [16,64)   P3 (over dead se) -> P4
    //   o        [0,16)    P4 (over dead h)  -> P5
    //   vT       [64,80)   P4a -> P4b
    //   W_emb_bf [48,52)   P0 -> P1 (dead before qkv write at P3)
    //   emb_bf   [58,74)   P0 -> P1 (dead before vT write at P4a)
    //   W_proj_bf[74,80)   P0 -> P3 (clobbered by vT at P4a, already dead)
    char* ws = (char*)d_ws;
    const size_t MB = 1024 * 1024;
    ushort_t* h       = (ushort_t*)(ws);
    ushort_t* se      = (ushort_t*)(ws + 16 * MB);
    ushort_t* qkv     = (ushort_t*)(ws + 16 * MB);
    ushort_t* o       = (ushort_t*)(ws);
    ushort_t* vT      = (ushort_t*)(ws + 64 * MB);
    ushort_t* wemb_bf = (ushort_t*)(ws + 48 * MB);
    ushort_t* emb_bf  = (ushort_t*)(ws + 58 * MB);
    ushort_t* wprj_bf = (ushort_t*)(ws + 74 * MB);
    const bool use_flash = (ws_size >= 80 * MB);

    const ushort_t* e0 = (const ushort_t*)x;
    const ushort_t* e1 = (const ushort_t*)emb;
    const ushort_t* e2 = (const ushort_t*)W_emb;
    const ushort_t* e3 = (const ushort_t*)W_proj;
    const ushort_t* e4 = (const ushort_t*)W_out;

    // 0) hoist dtype conversion out of GEMM K-loops (f32 -> bf16 once)
    cvt_bf16<<<2048, 256, 0, stream>>>(emb,    emb_bf,  ROWS * C_);
    cvt_bf16<<<1024, 256, 0, stream>>>(W_emb,  wemb_bf, 2 * C_ * C_);
    cvt_bf16<<<1024, 256, 0, stream>>>(W_proj, wprj_bf, 3 * C_ * C_);

    // 1) se = emb @ W_emb^T + b_emb        (8192 x 2048 x 1024), all-bf16 path
    gemm_bt<true, false, false, false, false, false><<<dim3(ROWS / 128, 2048 / 128), 256, 0, stream>>>(
        emb_bf, wemb_bf, (const ushort_t*)b_emb, nullptr, se, ROWS, 2048, 1024,
        e0, e1, e2, e3, e4);
    // 2) h = ln(x) * (1 + scale) + shift
    ln_film<<<ROWS, 256, 0, stream>>>(x, se, h);
    // 3) qkv = h @ W_proj^T, fused per-head LN of q,k   (8192 x 3072 x 1024)
    gemm_bt<false, false, false, false, false, true><<<dim3(ROWS / 128, 3072 / 128), 256, 0, stream>>>(
        h, wprj_bf, nullptr, nullptr, qkv, ROWS, 3072, 1024,
        e0, e1, e2, e3, e4);
    // 4) attention -> o (B,N,C)
    if (use_flash) {
        vtrans<<<dim3(B_ * H_, N_ / 64), 256, 0, stream>>>(qkv, vT);
        flash_attn<<<dim3(B_ * H_, N_ / 128), 512, 0, stream>>>(qkv, vT, o);
    } else {
        attn_simple<<<dim3(B_ * H_, N_ / 128), 256, 0, stream>>>(qkv, o);
    }
    // 5) out = o + o @ W_out^T             (8192 x 1024 x 1024)
    gemm_bt<false, true, false, true, true, false><<<dim3(ROWS / 128, 1024 / 128), 256, 0, stream>>>(
        o, W_out, nullptr, o, d_out, ROWS, 1024, 1024,
        e0, e1, e2, e3, e4);
}

// Round 14
// 462.850 us; speedup vs baseline: 1.2895x; 1.0677x over previous
//
#include <hip/hip_runtime.h>

#define B_ 4
#define N_ 2048
#define C_ 1024
#define H_ 16
#define D_ 64
#define ROWS (B_ * N_)   // 8192

typedef __bf16 bf16x8 __attribute__((ext_vector_type(8)));
typedef float f32x4 __attribute__((ext_vector_type(4)));
typedef unsigned short ushort_t;

__device__ inline float b2f(ushort_t u) {
    union { unsigned int i; float f; } v; v.i = ((unsigned int)u) << 16; return v.f;
}
// round-to-nearest-even f32 -> bf16
__device__ inline ushort_t f2b(float f) {
    union { float f; unsigned int i; } v; v.f = f;
    unsigned int r = v.i + 0x7fffu + ((v.i >> 16) & 1u);
    return (ushort_t)(r >> 16);
}
// HW packed f32x2 -> bf16x2 (RNE on gfx950); no builtin, inline asm per guide T12
__device__ inline unsigned int cvtpk(float a, float b) {
    unsigned int r;
    asm("v_cvt_pk_bf16_f32 %0, %1, %2" : "=v"(r) : "v"(a), "v"(b));
    return r;
}

// Runtime dtype detector: f32 arrays show huge bf16 exponents in even
// half-words; bf16 arrays of sane magnitude never do.
__device__ inline bool detect_f32(const ushort_t* u) {
    int huge = 0;
#pragma unroll
    for (int i = 0; i < 64; ++i) {
        int ex = (u[2 * i] >> 7) & 0xFF;
        huge |= (ex >= 0xC0) ? 1 : 0;
    }
    return huge != 0;
}

// ---------------------------------------------------------------------------
// Dtype hoist: convert an f32 (or copy a bf16) array to bf16 once, so GEMM
// staging runs the cheap bf16 path instead of per-tile f32->bf16 conversion.
// (Round-9 win: -124us total.)
// ---------------------------------------------------------------------------
__global__ __launch_bounds__(256) void cvt_bf16(
    const void* __restrict__ src, ushort_t* __restrict__ dst, int n_elts)
{
    const bool s32 = detect_f32((const ushort_t*)src);
    const int start = (blockIdx.x * 256 + threadIdx.x) * 8;
    const int stride = gridDim.x * 256 * 8;
    if (s32) {
        const float* s = (const float*)src;
        for (int i = start; i < n_elts; i += stride) {
            float4 a = *(const float4*)(s + i);
            float4 b = *(const float4*)(s + i + 4);
            ushort4 w0, w1;
            w0.x = f2b(a.x); w0.y = f2b(a.y); w0.z = f2b(a.z); w0.w = f2b(a.w);
            w1.x = f2b(b.x); w1.y = f2b(b.y); w1.z = f2b(b.z); w1.w = f2b(b.w);
            *(ushort4*)(dst + i)     = w0;
            *(ushort4*)(dst + i + 4) = w1;
        }
    } else {
        const ushort_t* s = (const ushort_t*)src;
        for (int i = start; i < n_elts; i += stride)
            *(uint4*)(dst + i) = *(const uint4*)(s + i);
    }
}

// ---------------------------------------------------------------------------
// GEMM: C[M,N] = A[M,K] * B[N,K]^T (+ bias[N]) (+ resid[M,N]).
// 128x128 tile, BK=32, 4 waves (2x2), each wave 64x64 = 4x4 subtiles.
// *** DO NOT use __builtin_amdgcn_global_load_lds here: 3/3 builds with it
//     (rounds 2,3,13) killed the MI355X container in this harness, vs 1/10
//     without. Usage was audited correct — harness/ROCm incompatibility. ***
// (Round-5 explicit double-buffer REGRESSED; round-10 XCD swizzle REGRESSED
//  — L3-resident working set, m160 regime gate.)
// LN_QK: fused per-head (64-col) LayerNorm of the f32 accumulators in the
// epilogue (wave's 64-col span == one head). OUT_DYN: f32 out iff all five
// external inputs are f32.
// ---------------------------------------------------------------------------
template<bool HAS_BIAS, bool HAS_RES, bool A_EXT, bool B_EXT, bool OUT_DYN, bool LN_QK>
__global__ __launch_bounds__(256) void gemm_bt(
    const void* __restrict__ A,
    const void* __restrict__ Bm,
    const ushort_t* __restrict__ bias,
    const ushort_t* __restrict__ resid,
    void* __restrict__ Cc,
    int M, int N, int K,
    const ushort_t* e0, const ushort_t* e1, const ushort_t* e2,
    const ushort_t* e3, const ushort_t* e4)
{
    const bool a32 = A_EXT ? detect_f32((const ushort_t*)A)  : false;
    const bool b32 = B_EXT ? detect_f32((const ushort_t*)Bm) : false;
    bool out32 = false;
    if constexpr (OUT_DYN)
        out32 = detect_f32(e0) && detect_f32(e1) && detect_f32(e2) &&
                detect_f32(e3) && detect_f32(e4);

    __shared__ __align__(16) ushort_t As[128][32];
    __shared__ __align__(16) ushort_t Bs[128][32];
    const int tid  = threadIdx.x;
    const int wave = tid >> 6, lane = tid & 63;
    const int lo = lane & 15, hi = lane >> 4;
    const int bm = blockIdx.x * 128, bn = blockIdx.y * 128;
    const int wm = (wave & 1) * 64,  wn = (wave >> 1) * 64;

    f32x4 acc[4][4] = {};

    for (int k0 = 0; k0 < K; k0 += 32) {
        if (a32) {
            const float* Af = (const float*)A;
#pragma unroll
            for (int i = 0; i < 4; ++i) {
                int c = tid + i * 256;
                int r = c >> 3, c4 = (c & 7) * 4;
                float4 v = *(const float4*)(Af + (size_t)(bm + r) * K + k0 + c4);
                ushort4 w; w.x = f2b(v.x); w.y = f2b(v.y); w.z = f2b(v.z); w.w = f2b(v.w);
                *(ushort4*)(&As[r][c4]) = w;
            }
        } else {
            const ushort_t* Ab = (const ushort_t*)A;
#pragma unroll
            for (int i = 0; i < 2; ++i) {
                int c = tid + i * 256;
                int r = c >> 2, c8 = (c & 3) * 8;
                *(uint4*)(&As[r][c8]) = *(const uint4*)(Ab + (size_t)(bm + r) * K + k0 + c8);
            }
        }
        if (b32) {
            const float* Bf = (const float*)Bm;
#pragma unroll
            for (int i = 0; i < 4; ++i) {
                int c = tid + i * 256;
                int r = c >> 3, c4 = (c & 7) * 4;
                float4 v = *(const float4*)(Bf + (size_t)(bn + r) * K + k0 + c4);
                ushort4 w; w.x = f2b(v.x); w.y = f2b(v.y); w.z = f2b(v.z); w.w = f2b(v.w);
                *(ushort4*)(&Bs[r][c4]) = w;
            }
        } else {
            const ushort_t* Bb = (const ushort_t*)Bm;
#pragma unroll
            for (int i = 0; i < 2; ++i) {
                int c = tid + i * 256;
                int r = c >> 2, c8 = (c & 3) * 8;
                *(uint4*)(&Bs[r][c8]) = *(const uint4*)(Bb + (size_t)(bn + r) * K + k0 + c8);
            }
        }
        __syncthreads();

        bf16x8 af[4], bfr[4];
#pragma unroll
        for (int i = 0; i < 4; ++i) af[i]  = *(const bf16x8*)(&As[wm + i * 16 + lo][hi * 8]);
#pragma unroll
        for (int j = 0; j < 4; ++j) bfr[j] = *(const bf16x8*)(&Bs[wn + j * 16 + lo][hi * 8]);
#pragma unroll
        for (int i = 0; i < 4; ++i)
#pragma unroll
            for (int j = 0; j < 4; ++j)
                acc[i][j] = __builtin_amdgcn_mfma_f32_16x16x32_bf16(af[i], bfr[j], acc[i][j], 0, 0, 0);
        __syncthreads();
    }

    if constexpr (LN_QK) {
        // per-head LN of q,k output columns (col0 = bn+wn, 64-aligned = 1 head)
        if (bn + wn < 2 * C_) {
#pragma unroll
            for (int i = 0; i < 4; ++i) {
#pragma unroll
                for (int r = 0; r < 4; ++r) {
                    float s = 0.0f, sq = 0.0f;
#pragma unroll
                    for (int j = 0; j < 4; ++j) {
                        float v = acc[i][j][r];
                        s += v; sq += v * v;
                    }
#pragma unroll
                    for (int off = 1; off < 16; off <<= 1) {
                        s  += __shfl_xor(s, off, 16);
                        sq += __shfl_xor(sq, off, 16);
                    }
                    const float mu   = s * (1.0f / 64.0f);
                    const float var  = sq * (1.0f / 64.0f) - mu * mu;
                    const float rstd = rsqrtf(var + 1e-5f);
#pragma unroll
                    for (int j = 0; j < 4; ++j)
                        acc[i][j][r] = (acc[i][j][r] - mu) * rstd;
                }
            }
        }
    }

#pragma unroll
    for (int i = 0; i < 4; ++i) {
#pragma unroll
        for (int j = 0; j < 4; ++j) {
            const int n = bn + wn + j * 16 + lo;
            float bv = HAS_BIAS ? b2f(bias[n]) : 0.0f;
#pragma unroll
            for (int r = 0; r < 4; ++r) {
                const int m = bm + wm + i * 16 + hi * 4 + r;
                float v = acc[i][j][r] + bv;
                if (HAS_RES) v += b2f(resid[(size_t)m * N + n]);
                if (OUT_DYN && out32) ((float*)Cc)[(size_t)m * N + n] = v;
                else                  ((ushort_t*)Cc)[(size_t)m * N + n] = f2b(v);
            }
        }
    }
}

// ---------------------------------------------------------------------------
// Fused LayerNorm(x) + FiLM: h = ln(x) * (1 + scale) + shift.
// ---------------------------------------------------------------------------
__global__ __launch_bounds__(256) void ln_film(
    const void* __restrict__ x,
    const ushort_t* __restrict__ se,
    ushort_t* __restrict__ h)
{
    const bool x32 = detect_f32((const ushort_t*)x);
    const int row = blockIdx.x;
    const int t = threadIdx.x;
    const int wave = t >> 6, lane = t & 63;

    float f0, f1, f2, f3;
    if (x32) {
        float4 v = *(const float4*)((const float*)x + (size_t)row * C_ + t * 4);
        f0 = v.x; f1 = v.y; f2 = v.z; f3 = v.w;
    } else {
        ushort4 v = *(const ushort4*)((const ushort_t*)x + (size_t)row * C_ + t * 4);
        f0 = b2f(v.x); f1 = b2f(v.y); f2 = b2f(v.z); f3 = b2f(v.w);
    }
    float s  = f0 + f1 + f2 + f3;
    float sq = f0 * f0 + f1 * f1 + f2 * f2 + f3 * f3;
#pragma unroll
    for (int off = 32; off >= 1; off >>= 1) {
        s  += __shfl_xor(s, off);
        sq += __shfl_xor(sq, off);
    }
    __shared__ float red[8];
    if (lane == 0) { red[wave] = s; red[4 + wave] = sq; }
    __syncthreads();
    s  = red[0] + red[1] + red[2] + red[3];
    sq = red[4] + red[5] + red[6] + red[7];
    const float mu   = s * (1.0f / C_);
    const float var  = sq * (1.0f / C_) - mu * mu;
    const float rstd = rsqrtf(var + 1e-5f);

    const ushort_t* ser = se + (size_t)row * (2 * C_);
    ushort4 sc = *(const ushort4*)(ser + t * 4);
    ushort4 sh = *(const ushort4*)(ser + C_ + t * 4);
    ushort4 out;
    out.x = f2b((f0 - mu) * rstd * (1.0f + b2f(sc.x)) + b2f(sh.x));
    out.y = f2b((f1 - mu) * rstd * (1.0f + b2f(sc.y)) + b2f(sh.y));
    out.z = f2b((f2 - mu) * rstd * (1.0f + b2f(sc.z)) + b2f(sh.z));
    out.w = f2b((f3 - mu) * rstd * (1.0f + b2f(sc.w)) + b2f(sh.w));
    *(ushort4*)(h + (size_t)row * C_ + t * 4) = out;
}

// ---------------------------------------------------------------------------
// V transpose: qkv (B,N,3,H,D) v-section -> vT (B,H,D,N). Coalesced both
// ways via LDS 64x64 tile. Grid: (B*H, N/64), 256 threads.
// ---------------------------------------------------------------------------
__global__ __launch_bounds__(256) void vtrans(
    const ushort_t* __restrict__ qkv,
    ushort_t* __restrict__ vT)
{
    const int bh = blockIdx.x, b = bh >> 4, hh = bh & 15;
    const int n0 = blockIdx.y * 64;
    const int t = threadIdx.x;
    __shared__ ushort_t Vs[64][65];

    const int r = t >> 2, c0 = (t & 3) * 16;   // row 0..63, col chunk of 16
    const ushort_t* src = qkv + (size_t)(b * N_ + n0 + r) * (3 * C_) + 2 * C_ + hh * D_;
#pragma unroll
    for (int i = 0; i < 16; ++i) Vs[r][c0 + i] = src[c0 + i];
    __syncthreads();
    // write rows of vT: thread t -> d = t>>2, n chunk (t&3)*16
    const int d = t >> 2, j0 = (t & 3) * 16;
    ushort_t* dst = vT + ((size_t)bh * D_ + d) * N_ + n0;
#pragma unroll
    for (int i = 0; i < 16; ++i) dst[j0 + i] = Vs[j0 + i][d];
}

// ---------------------------------------------------------------------------
// Flash attention v9 (8-wave, single-buffer, VALU-thinned softmax).
// (Round-12: 216 -> 126.5us. Unchanged.)
// Grid: (B*H, N/128). 512 threads = 8 waves, 16 q-rows each.
//  (1) SC scale folded into Q fragments once at load
//  (2) defer-max check on LANE-LOCAL max; full reduce only in rare branch
//  (3) lane-local l partial sums; single 16-lane reduce at epilogue
//  (4) v_cvt_pk_bf16_f32 (HW RNE) for P->bf16
// Single K/V LDS buffer (34KB) + T14 reg-held next tile + 2 barriers/tile.
// XOR-swizzled K/V LDS (chunk ^= row&7). P via wave-private padded slice.
// ---------------------------------------------------------------------------
__global__ __launch_bounds__(512) void flash_attn(
    const ushort_t* __restrict__ qkv,
    const ushort_t* __restrict__ vT,
    ushort_t* __restrict__ o)
{
    const int bh = blockIdx.x, b = bh >> 4, hh = bh & 15;
    const int qb = blockIdx.y;
    const int tid = threadIdx.x;
    const int wave = tid >> 6, lane = tid & 63;
    const int lo = lane & 15, hi = lane >> 4;

    __shared__ __align__(16) ushort_t Ks[64 * 64];      // 8KB, swizzled chunks
    __shared__ __align__(16) ushort_t Vsh[64 * 64];     // 8KB
    __shared__ __align__(16) ushort_t Pl[8][16][72];    // wave-private, padded

    // staging slot geometry: slot s (0..511) = one 16B chunk; row r=s>>3, chunk c=s&7
    const int sr = tid >> 3, sc = tid & 7;
    const int lsw = sr * 64 + ((sc ^ (sr & 7)) * 8);    // swizzled ushort offset

    const int qrow = qb * 128 + wave * 16;
    // Q fragment (A-layout), pre-scaled by SC = 1/sqrt(64)*log2(e) so QK^T
    // lands directly in the exp2 domain (VALU cut #1).
    const float SC = 0.125f * 1.44269504f;
    const ushort_t* qp = qkv + (size_t)(b * N_ + qrow + lo) * (3 * C_) + hh * D_;
    bf16x8 a0 = *(const bf16x8*)(qp + hi * 8);
    bf16x8 a1 = *(const bf16x8*)(qp + 32 + hi * 8);
#pragma unroll
    for (int i = 0; i < 8; ++i) {
        a0[i] = (__bf16)((float)a0[i] * SC);
        a1[i] = (__bf16)((float)a1[i] * SC);
    }

    // staging bases: K rows are keys (stride 3C); V rows are d (stride N)
    const ushort_t* Kg = qkv + (size_t)b * N_ * (3 * C_) + C_ + hh * D_;
    const ushort_t* Vg = vT + (size_t)bh * D_ * N_;

    f32x4 accO[4] = {};
    float m_r[4], l_p[4];                      // running max, LANE-LOCAL l partials
#pragma unroll
    for (int r = 0; r < 4; ++r) { m_r[r] = -1e30f; l_p[r] = 0.0f; }
    const f32x4 zero = {0.f, 0.f, 0.f, 0.f};

    // swizzled read chunk offsets (in ushorts): chunks hi and 4+hi of a row,
    // row&7 == lo&7 for every fragment row this lane touches
    const int q0 = (hi ^ (lo & 7)) * 8;
    const int q1 = ((4 + hi) ^ (lo & 7)) * 8;

    // ---- prologue: stage tile 0 ----
    uint4 kst, vst;
    kst = *(const uint4*)(Kg + (size_t)sr * (3 * C_) + sc * 8);
    vst = *(const uint4*)(Vg + (size_t)sr * N_ + sc * 8);
    *(uint4*)(&Ks[lsw])  = kst;
    *(uint4*)(&Vsh[lsw]) = vst;
    __syncthreads();

    for (int kt = 0; kt < N_; kt += 64) {
        // T14 issue-early: launch tile t+1 global loads before compute
        const bool more = (kt + 64 < N_);
        if (more) {
            kst = *(const uint4*)(Kg + (size_t)(kt + 64 + sr) * (3 * C_) + sc * 8);
            vst = *(const uint4*)(Vg + (size_t)sr * N_ + (kt + 64) + sc * 8);
        }
        __builtin_amdgcn_sched_barrier(0);   // keep load issue above compute

        // ---- QK^T for 4 groups of 16 keys (already exp2-domain via Q scale) ----
        f32x4 S[4];
#pragma unroll
        for (int g = 0; g < 4; ++g) {
            const int R = g * 16 + lo;
            bf16x8 kl = *(const bf16x8*)(Ks + R * 64 + q0);
            bf16x8 kh = *(const bf16x8*)(Ks + R * 64 + q1);
            f32x4 s0 = __builtin_amdgcn_mfma_f32_16x16x32_bf16(a0, kl, zero, 0, 0, 0);
            S[g]     = __builtin_amdgcn_mfma_f32_16x16x32_bf16(a1, kh, s0,   0, 0, 0);
        }

        // ---- online softmax: lane-local defer-max ----
        float mx[4];
        int needi = 0;
#pragma unroll
        for (int r = 0; r < 4; ++r) {
            mx[r] = fmaxf(fmaxf(S[0][r], S[1][r]), fmaxf(S[2][r], S[3][r]));
            needi |= (mx[r] > m_r[r] + 11.0f) ? 1 : 0;
        }
        if (__any(needi)) {
            // rare: full row-max reduce + rescale (alpha row-uniform)
#pragma unroll
            for (int r = 0; r < 4; ++r) {
                float fm = mx[r];
#pragma unroll
                for (int off = 1; off < 16; off <<= 1) fm = fmaxf(fm, __shfl_xor(fm, off, 16));
                float mnew  = fmaxf(m_r[r], fm);
                float alpha = __builtin_amdgcn_exp2f(m_r[r] - mnew);
                m_r[r] = mnew;
                l_p[r] *= alpha;
#pragma unroll
                for (int ds = 0; ds < 4; ++ds) accO[ds][r] *= alpha;
            }
        }
#pragma unroll
        for (int r = 0; r < 4; ++r) {
            float p0 = __builtin_amdgcn_exp2f(S[0][r] - m_r[r]);
            float p1 = __builtin_amdgcn_exp2f(S[1][r] - m_r[r]);
            float p2 = __builtin_amdgcn_exp2f(S[2][r] - m_r[r]);
            float p3 = __builtin_amdgcn_exp2f(S[3][r] - m_r[r]);
            unsigned int c01 = cvtpk(p0, p1);
            unsigned int c23 = cvtpk(p2, p3);
            ushort_t* prow = &Pl[wave][hi * 4 + r][lo];
            prow[0]  = (ushort_t)(c01 & 0xffffu);
            prow[16] = (ushort_t)(c01 >> 16);
            prow[32] = (ushort_t)(c23 & 0xffffu);
            prow[48] = (ushort_t)(c23 >> 16);
            l_p[r] += (p0 + p1) + (p2 + p3);
        }

        // intra-wave LDS RAW fence for Pl (wave-private slice, no barrier)
        asm volatile("s_waitcnt lgkmcnt(0)" ::: "memory");
        __builtin_amdgcn_sched_barrier(0);

        // ---- PV: P (16x64) x V^T tile (64d x 64k) ----
        bf16x8 pf0 = *(const bf16x8*)(&Pl[wave][lo][hi * 8]);        // keys 0..31
        bf16x8 pf1 = *(const bf16x8*)(&Pl[wave][lo][32 + hi * 8]);   // keys 32..63
#pragma unroll
        for (int ds = 0; ds < 4; ++ds) {
            const int R = ds * 16 + lo;
            bf16x8 vf0 = *(const bf16x8*)(Vsh + R * 64 + q0);
            bf16x8 vf1 = *(const bf16x8*)(Vsh + R * 64 + q1);
            accO[ds] = __builtin_amdgcn_mfma_f32_16x16x32_bf16(pf0, vf0, accO[ds], 0, 0, 0);
            accO[ds] = __builtin_amdgcn_mfma_f32_16x16x32_bf16(pf1, vf1, accO[ds], 0, 0, 0);
        }

        // ---- write-late: overwrite the single buffer with the next tile ----
        if (more) {
            __syncthreads();                   // all waves done reading LDS
            *(uint4*)(&Ks[lsw])  = kst;
            *(uint4*)(&Vsh[lsw]) = vst;
            __syncthreads();                   // next tile visible to all
        }
    }

    // epilogue: reduce the lane-local l partials once
    float l_r[4];
#pragma unroll
    for (int r = 0; r < 4; ++r) {
        float l = l_p[r];
#pragma unroll
        for (int off = 1; off < 16; off <<= 1) l += __shfl_xor(l, off, 16);
        l_r[r] = l;
    }

#pragma unroll
    for (int ds = 0; ds < 4; ++ds)
#pragma unroll
        for (int r = 0; r < 4; ++r) {
            const int row = qrow + hi * 4 + r;
            float val = accO[ds][r] / l_r[r];
            o[((size_t)(b * N_ + row)) * C_ + hh * D_ + ds * 16 + lo] = f2b(val);
        }
}

// ---------------------------------------------------------------------------
// Fallback simple attention (proven correct, slow) for small workspaces.
// ---------------------------------------------------------------------------
__global__ __launch_bounds__(256) void attn_simple(
    const ushort_t* __restrict__ qkv,
    ushort_t* __restrict__ o)
{
    const int bh = blockIdx.x, b = bh >> 4, hh = bh & 15;
    const int t = threadIdx.x, lane = t & 63, wave = t >> 6;
    __shared__ float sc[N_];
    __shared__ float qrow[D_];
    __shared__ float red[4];
    __shared__ float opart[4][D_];

    const size_t hbase = (size_t)b * N_ * (3 * C_) + (size_t)hh * D_;

    for (int qi = 0; qi < 128; ++qi) {
        const int qr = blockIdx.y * 128 + qi;
        if (t < 64) qrow[t] = b2f(qkv[hbase + (size_t)qr * (3 * C_) + t]);
        __syncthreads();

        float myS[8];
        float mymax = -1e30f;
#pragma unroll
        for (int jj = 0; jj < 8; ++jj) {
            const int j = t + jj * 256;
            const bf16x8* kr = (const bf16x8*)(qkv + hbase + (size_t)j * (3 * C_) + C_);
            float s = 0.0f;
#pragma unroll
            for (int c = 0; c < 8; ++c) {
                bf16x8 kv = kr[c];
#pragma unroll
                for (int e = 0; e < 8; ++e) s += qrow[c * 8 + e] * (float)kv[e];
            }
            s *= 0.125f;
            myS[jj] = s;
            mymax = fmaxf(mymax, s);
        }
#pragma unroll
        for (int off = 32; off >= 1; off >>= 1) mymax = fmaxf(mymax, __shfl_xor(mymax, off));
        if (lane == 0) red[wave] = mymax;
        __syncthreads();
        const float M = fmaxf(fmaxf(red[0], red[1]), fmaxf(red[2], red[3]));

        float mysum = 0.0f;
#pragma unroll
        for (int jj = 0; jj < 8; ++jj) {
            float p = __expf(myS[jj] - M);
            sc[t + jj * 256] = p;
            mysum += p;
        }
#pragma unroll
        for (int off = 32; off >= 1; off >>= 1) mysum += __shfl_xor(mysum, off);
        __syncthreads();
        if (lane == 0) red[wave] = mysum;
        __syncthreads();
        const float L = red[0] + red[1] + red[2] + red[3];

        float acc = 0.0f;
        const int d = lane;
        const ushort_t* vb = qkv + hbase + 2 * C_ + d;
        for (int j = wave * 512; j < wave * 512 + 512; ++j)
            acc += sc[j] * b2f(vb[(size_t)j * (3 * C_)]);
        opart[wave][d] = acc;
        __syncthreads();
        if (t < 64) {
            float val = (opart[0][t] + opart[1][t] + opart[2][t] + opart[3][t]) / L;
            o[((size_t)(b * N_ + qr)) * C_ + hh * D_ + t] = f2b(val);
        }
        __syncthreads();
    }
}

// ---------------------------------------------------------------------------
extern "C" void kernel_launch(void* const* d_in, const int* in_sizes, int n_in,
                              void* d_out, int out_size, void* d_ws, size_t ws_size,
                              hipStream_t stream)
{
    const void* x = nullptr; const void* emb = nullptr;
    const void* W_emb = nullptr; const void* b_emb = nullptr;
    const void* W_proj = nullptr; const void* W_out = nullptr;
    int big_seen = 0;
    for (int i = 0; i < n_in; ++i) {
        const int s = in_sizes[i];
        if      (s == ROWS * C_)   { if (big_seen++ == 0) x = d_in[i]; else emb = d_in[i]; }
        else if (s == 2 * C_ * C_) W_emb  = d_in[i];
        else if (s == 3 * C_ * C_) W_proj = d_in[i];
        else if (s == C_ * C_)     W_out  = d_in[i];
        else if (s == 2 * C_)      b_emb  = d_in[i];
    }

    // Workspace (80 MB budget), with dtype-hoisted bf16 copies:
    //   h        [0,16)    P2 -> P3
    //   se       [16,48)   P1 -> P2
    //   qkv      [16,64)   P3 (over dead se) -> P4
    //   o        [0,16)    P4 (over dead h)  -> P5
    //   vT       [64,80)   P4a -> P4b
    //   W_emb_bf [48,52)   P0 -> P1 (dead before qkv write at P3)
    //   emb_bf   [58,74)   P0 -> P1 (dead before qkv/vT writes)
    //   W_proj_bf[74,80)   P0 -> P3 (clobbered by vT at P4a, already dead)
    //   W_out_bf [64,66)   P4c -> P5 (over dead vT, after flash completes)
    char* ws = (char*)d_ws;
    const size_t MB = 1024 * 1024;
    ushort_t* h       = (ushort_t*)(ws);
    ushort_t* se      = (ushort_t*)(ws + 16 * MB);
    ushort_t* qkv     = (ushort_t*)(ws + 16 * MB);
    ushort_t* o       = (ushort_t*)(ws);
    ushort_t* vT      = (ushort_t*)(ws + 64 * MB);
    ushort_t* wemb_bf = (ushort_t*)(ws + 48 * MB);
    ushort_t* emb_bf  = (ushort_t*)(ws + 58 * MB);
    ushort_t* wprj_bf = (ushort_t*)(ws + 74 * MB);
    ushort_t* wout_bf = (ushort_t*)(ws + 64 * MB);
    const bool use_flash = (ws_size >= 80 * MB);

    const ushort_t* e0 = (const ushort_t*)x;
    const ushort_t* e1 = (const ushort_t*)emb;
    const ushort_t* e2 = (const ushort_t*)W_emb;
    const ushort_t* e3 = (const ushort_t*)W_proj;
    const ushort_t* e4 = (const ushort_t*)W_out;

    // 0) hoist dtype conversion out of GEMM K-loops (f32 -> bf16 once)
    cvt_bf16<<<2048, 256, 0, stream>>>(emb,    emb_bf,  ROWS * C_);
    cvt_bf16<<<1024, 256, 0, stream>>>(W_emb,  wemb_bf, 2 * C_ * C_);
    cvt_bf16<<<1024, 256, 0, stream>>>(W_proj, wprj_bf, 3 * C_ * C_);

    // 1) se = emb @ W_emb^T + b_emb        (8192 x 2048 x 1024), all-bf16 path
    gemm_bt<true, false, false, false, false, false><<<dim3(ROWS / 128, 2048 / 128), 256, 0, stream>>>(
        emb_bf, wemb_bf, (const ushort_t*)b_emb, nullptr, se, ROWS, 2048, 1024,
        e0, e1, e2, e3, e4);
    // 2) h = ln(x) * (1 + scale) + shift
    ln_film<<<ROWS, 256, 0, stream>>>(x, se, h);
    // 3) qkv = h @ W_proj^T, fused per-head LN of q,k   (8192 x 3072 x 1024)
    gemm_bt<false, false, false, false, false, true><<<dim3(ROWS / 128, 3072 / 128), 256, 0, stream>>>(
        h, wprj_bf, nullptr, nullptr, qkv, ROWS, 3072, 1024,
        e0, e1, e2, e3, e4);
    // 4) attention -> o (B,N,C)
    if (use_flash) {
        vtrans<<<dim3(B_ * H_, N_ / 64), 256, 0, stream>>>(qkv, vT);
        flash_attn<<<dim3(B_ * H_, N_ / 128), 512, 0, stream>>>(qkv, vT, o);
        // 4c) hoist W_out conversion into the dead vT region
        cvt_bf16<<<512, 256, 0, stream>>>(W_out, wout_bf, C_ * C_);
        // 5) out = o + o @ W_out^T         (8192 x 1024 x 1024), all-bf16 path
        gemm_bt<false, true, false, false, true, false><<<dim3(ROWS / 128, 1024 / 128), 256, 0, stream>>>(
            o, wout_bf, nullptr, o, d_out, ROWS, 1024, 1024,
            e0, e1, e2, e3, e4);
    } else {
        attn_simple<<<dim3(B_ * H_, N_ / 128), 256, 0, stream>>>(qkv, o);
        gemm_bt<false, true, false, true, true, false><<<dim3(ROWS / 128, 1024 / 128), 256, 0, stream>>>(
            o, W_out, nullptr, o, d_out, ROWS, 1024, 1024,
            e0, e1, e2, e3, e4);
    }
}